// Round 9
// baseline (39.420 us; speedup 1.0000x reference)
//
#include <hip/hip_runtime.h>

#define LD 68  // fp32 LDS row stride: 272B = 17x16B
#define XP 72  // bf16 X row pitch: 144B = 9x16B, conflict-free frag reads

typedef float f32x4 __attribute__((ext_vector_type(4)));
typedef short s16x8 __attribute__((ext_vector_type(8)));
typedef unsigned long long u64;

__device__ __forceinline__ unsigned short f2bf(float f) {
  union { float f; unsigned int u; } v; v.f = f;
  const unsigned int r = (v.u + 0x7fffu + ((v.u >> 16) & 1u)) >> 16;
  return (unsigned short)r;
}
__device__ __forceinline__ float bf2f(unsigned short h) {
  union { unsigned int u; float f; } v; v.u = ((unsigned int)h) << 16;
  return v.f;
}

__global__ __launch_bounds__(512) void lagat_kernel(
    const float* __restrict__ adj,
    const float* __restrict__ feat_node,
    const int* __restrict__ idx,
    const int* __restrict__ head_ids,
    const int* __restrict__ tail_ids,
    const float* __restrict__ transform,
    const float* __restrict__ embed,
    const float* __restrict__ w1, const float* __restrict__ b1,
    const float* __restrict__ w2, const float* __restrict__ b2,
    const float* __restrict__ gamma1, const float* __restrict__ beta1,
    const float* __restrict__ gamma2, const float* __restrict__ beta2,
    float* __restrict__ out)
{
  __shared__ __align__(16) float featb[64][LD];  // transformed features
  __shared__ __align__(16) float Sb[2][64][LD];  // head/tail running state
  __shared__ __align__(16) float Ib[64][LD];     // init_feat scratch
  __shared__ __align__(16) unsigned short Xh[2][64][XP];  // X hi (bf16)
  __shared__ __align__(16) unsigned short Xl[2][64][XP];  // X lo (bf16)
  __shared__ float prm[2][3][64];                // gamma, beta, bias per chain
  __shared__ u64 adjbits[64];                    // adjacency bit-rows
  __shared__ u64 lev[2][3];                      // BFS reach masks
  __shared__ float degs[64];
  __shared__ float corr[2][64];

  const int g = blockIdx.x, tid = threadIdx.x, nb = g * 64;
  const int wv = tid >> 6, lane = tid & 63;

  // ---- P0: adjacency -> bit rows (ballot); init_feat, prm -> LDS ----
  {
#pragma unroll
    for (int rr = 0; rr < 8; ++rr) {
      const int i = wv * 8 + rr;
      const float v = adj[(size_t)(nb + i) * 4096 + nb + lane];
      const u64 b = __ballot(v != 0.0f);
      if (lane == 0) adjbits[i] = b;
    }
  }
  {
    const int r = tid >> 3, c8 = (tid & 7) * 8;
    if (c8 < 32) {
      const float4* fs = (const float4*)&feat_node[(size_t)(nb + r) * 32 + c8];
      *(float4*)&Ib[r][c8]     = fs[0];
      *(float4*)&Ib[r][c8 + 4] = fs[1];
    } else {
      const float4* es = (const float4*)&embed[(size_t)idx[nb + r] * 32 + (c8 - 32)];
      *(float4*)&Ib[r][c8]     = es[0];
      *(float4*)&Ib[r][c8 + 4] = es[1];
    }
  }
  if (tid < 384) {
    const int a = tid >> 6, h = tid & 63;
    const float* s6 = (a == 0) ? gamma1 : (a == 1) ? beta1 : (a == 2) ? b1
                    : (a == 3) ? gamma2 : (a == 4) ? beta2 : b2;
    prm[a / 3][a % 3][h] = s6[h];
  }
  __syncthreads();

  const int hl = head_ids[g] - nb, tl = tail_ids[g] - nb;

  // ---- E-phase wave mapping + W fragments from global (once) ----
  const int ech = wv >> 2, eslab = (wv & 3) * 16;
  const int ln15 = lane & 15, lg = lane >> 4;
  s16x8 wfh[8], wfl[8];   // [ct*2+ks], hi/lo bf16 B-frags, persist in VGPRs
  float ebias[4];
  {
    const float* Wg = ech ? w2 : w1;
#pragma unroll
    for (int ct = 0; ct < 4; ++ct) {
#pragma unroll
      for (int ks = 0; ks < 2; ++ks) {
        s16x8 h, lo;
#pragma unroll
        for (int j = 0; j < 8; ++j) {
          const float w = Wg[(size_t)(ks * 32 + lg * 8 + j) * 64 + ct * 16 + ln15];
          const unsigned short hu = f2bf(w);
          h[j] = (short)hu;
          lo[j] = (short)f2bf(w - bf2f(hu));
        }
        wfh[ct * 2 + ks] = h;
        wfl[ct * 2 + ks] = lo;
      }
    }
  }

  // ---- P1: degs (popcount) + BFS reach (bit ops) || transform GEMM ----
  if (tid < 64) degs[tid] = (float)__popcll(adjbits[tid]);
  if (tid >= 128 && tid < 256) {   // waves 2-3: per-chain BFS
    const int c = (tid >> 6) - 2;
    const int root = c ? tl : hl;
    const u64 l0 = 1ull << root;
    const u64 l1 = l0 | adjbits[root];
    u64 cand = ((l1 >> lane) & 1ull) ? adjbits[lane] : 0ull;
#pragma unroll
    for (int m = 1; m < 64; m <<= 1) cand |= __shfl_xor(cand, m, 64);
    if (lane == 0) { lev[c][0] = l0; lev[c][1] = l1; lev[c][2] = l0 | cand; }
  }
  {
    const int c0g = (tid & 15) * 4, r0g = (tid >> 4) * 2;
    float a0c[4] = {}, a1c[4] = {};
    for (int k = 0; k < 64; ++k) {
      const float4 t4 = *(const float4*)&transform[(size_t)k * 64 + c0g];
      const float a0 = Ib[r0g][k], a1 = Ib[r0g + 1][k];
      a0c[0] = fmaf(a0, t4.x, a0c[0]); a0c[1] = fmaf(a0, t4.y, a0c[1]);
      a0c[2] = fmaf(a0, t4.z, a0c[2]); a0c[3] = fmaf(a0, t4.w, a0c[3]);
      a1c[0] = fmaf(a1, t4.x, a1c[0]); a1c[1] = fmaf(a1, t4.y, a1c[1]);
      a1c[2] = fmaf(a1, t4.z, a1c[2]); a1c[3] = fmaf(a1, t4.w, a1c[3]);
    }
    *(float4*)&featb[r0g][c0g]     = make_float4(a0c[0], a0c[1], a0c[2], a0c[3]);
    *(float4*)&featb[r0g + 1][c0g] = make_float4(a1c[0], a1c[1], a1c[2], a1c[3]);
  }
  __syncthreads();

  // ---- P2: S init + layer-0 write ----
  {
    const int r = tid >> 3, c8 = (tid & 7) * 8;
#pragma unroll
    for (int u = 0; u < 2; ++u) {
      const float4 v = *(const float4*)&featb[r][c8 + 4 * u];
      *(float4*)&Sb[0][r][c8 + 4 * u] = v;
      *(float4*)&Sb[1][r][c8 + 4 * u] = v;
      *(float4*)&out[(size_t)(nb + r) * 256 + c8 + 4 * u] = v;
    }
  }
#pragma unroll
  for (int ct = 0; ct < 4; ++ct) ebias[ct] = prm[ech][2][ct * 16 + ln15];
  __syncthreads();

  // ---- hop-loop mappings + register preloads (loop-invariant) ----
  const int ch = tid >> 8, t = tid & 255;
  const int c0 = (t & 15) * 4, r0 = (t >> 4) * 4;  // 4x4 tile (B/D)
  const int iA = t >> 2, qA = t & 3;               // A-phase map
  const int qrow = ch ? hl : tl;                   // opposite-center query
  const int r8 = tid >> 3, cc8 = (tid & 7) * 8;    // layer-write map

  u64 rb[4];
  float dn[4], ga[4], be[4];
  float4 ft[4], qv[4];
#pragma unroll
  for (int m = 0; m < 4; ++m) {
    rb[m] = adjbits[r0 + m];
    dn[m] = 1.f / (degs[r0 + m] + 1e-8f);
    ft[m] = *(const float4*)&featb[r0 + m][c0];
  }
#pragma unroll
  for (int c = 0; c < 4; ++c) {
    ga[c] = prm[ch][0][c0 + c];
    be[c] = prm[ch][1][c0 + c];
  }
#pragma unroll
  for (int u = 0; u < 4; ++u)
    qv[u] = *(const float4*)&featb[qrow][qA * 16 + 4 * u];

  for (int hop = 2; hop >= 0; --hop) {
    // deferred layer write (L = 2-hop) + A: corr[i] = |dot(q, S[i])|
    if (hop != 2) {
      const int L = 2 - hop;
#pragma unroll
      for (int u = 0; u < 2; ++u) {
        const float4 a = *(const float4*)&Sb[0][r8][cc8 + 4 * u];
        const float4 b = *(const float4*)&Sb[1][r8][cc8 + 4 * u];
        *(float4*)&out[(size_t)(nb + r8) * 256 + (size_t)L * 64 + cc8 + 4 * u] =
            make_float4(a.x + b.x, a.y + b.y, a.z + b.z, a.w + b.w);
      }
    }
    {
      float s = 0.f;
#pragma unroll
      for (int u = 0; u < 4; ++u) {
        const float4 sv = *(const float4*)&Sb[ch][iA][qA * 16 + 4 * u];
        s = fmaf(qv[u].x, sv.x, s); s = fmaf(qv[u].y, sv.y, s);
        s = fmaf(qv[u].z, sv.z, s); s = fmaf(qv[u].w, sv.w, s);
      }
      s += __shfl_xor(s, 1);
      s += __shfl_xor(s, 2);
      if (qA == 0) corr[ch][iA] = fabsf(s);
    }
    __syncthreads();

    // B+C+D fused, 4x4 register tile, adjacency from bit-registers
    {
      float acc[4][4] = {};
      u64 t0 = rb[0], t1 = rb[1], t2 = rb[2], t3 = rb[3];
      for (int j = 0; j < 64; ++j) {
        const float cj = corr[ch][j];
        const float4 s4 = *(const float4*)&Sb[ch][j][c0];
        const float w0 = (t0 & 1ull) ? cj : 0.f;
        const float w1_ = (t1 & 1ull) ? cj : 0.f;
        const float w2_ = (t2 & 1ull) ? cj : 0.f;
        const float w3_ = (t3 & 1ull) ? cj : 0.f;
        t0 >>= 1; t1 >>= 1; t2 >>= 1; t3 >>= 1;
        acc[0][0] = fmaf(w0, s4.x, acc[0][0]); acc[0][1] = fmaf(w0, s4.y, acc[0][1]);
        acc[0][2] = fmaf(w0, s4.z, acc[0][2]); acc[0][3] = fmaf(w0, s4.w, acc[0][3]);
        acc[1][0] = fmaf(w1_, s4.x, acc[1][0]); acc[1][1] = fmaf(w1_, s4.y, acc[1][1]);
        acc[1][2] = fmaf(w1_, s4.z, acc[1][2]); acc[1][3] = fmaf(w1_, s4.w, acc[1][3]);
        acc[2][0] = fmaf(w2_, s4.x, acc[2][0]); acc[2][1] = fmaf(w2_, s4.y, acc[2][1]);
        acc[2][2] = fmaf(w2_, s4.z, acc[2][2]); acc[2][3] = fmaf(w2_, s4.w, acc[2][3]);
        acc[3][0] = fmaf(w3_, s4.x, acc[3][0]); acc[3][1] = fmaf(w3_, s4.y, acc[3][1]);
        acc[3][2] = fmaf(w3_, s4.z, acc[3][2]); acc[3][3] = fmaf(w3_, s4.w, acc[3][3]);
      }
      float x[4][4], sm[4], s2[4];
#pragma unroll
      for (int m = 0; m < 4; ++m) {
        float smm = 0.f, s2m = 0.f;
#pragma unroll
        for (int c = 0; c < 4; ++c) {
          float z = acc[m][c];
          z = (z > 0.f) ? z : 0.01f * z;   // leaky_relu slope 0.01
          z *= dn[m];
          x[m][c] = z; smm += z; s2m = fmaf(z, z, s2m);
        }
        sm[m] = smm; s2[m] = s2m;
      }
#pragma unroll
      for (int mask = 1; mask < 16; mask <<= 1) {
#pragma unroll
        for (int m = 0; m < 4; ++m) {
          sm[m] += __shfl_xor(sm[m], mask);
          s2[m] += __shfl_xor(s2[m], mask);
        }
      }
      const u64 fmask = lev[ch][hop];
#pragma unroll
      for (int m = 0; m < 4; ++m) {
        const float mu = sm[m] * 0.015625f;
        const float var = fmaxf(s2[m] * 0.015625f - mu * mu, 0.f);
        const float rstd = rsqrtf(var + 1e-5f);
        const float f = (float)((fmask >> (r0 + m)) & 1ull);
        float xv[4];
        xv[0] = fmaf(f, ft[m].x, ga[0] * (x[m][0] - mu) * rstd + be[0]);
        xv[1] = fmaf(f, ft[m].y, ga[1] * (x[m][1] - mu) * rstd + be[1]);
        xv[2] = fmaf(f, ft[m].z, ga[2] * (x[m][2] - mu) * rstd + be[2]);
        xv[3] = fmaf(f, ft[m].w, ga[3] * (x[m][3] - mu) * rstd + be[3]);
        ushort4 h4, l4;
        h4.x = f2bf(xv[0]); l4.x = f2bf(xv[0] - bf2f(h4.x));
        h4.y = f2bf(xv[1]); l4.y = f2bf(xv[1] - bf2f(h4.y));
        h4.z = f2bf(xv[2]); l4.z = f2bf(xv[2] - bf2f(h4.z));
        h4.w = f2bf(xv[3]); l4.w = f2bf(xv[3] - bf2f(h4.w));
        *(ushort4*)&Xh[ch][r0 + m][c0] = h4;
        *(ushort4*)&Xl[ch][r0 + m][c0] = l4;
      }
    }
    __syncthreads();

    // E (MFMA): S[i] = f ? relu(X[i] @ W + b) : S[i]
    {
      s16x8 xhf[2], xlf[2];
      const int xrow = eslab + ln15;
#pragma unroll
      for (int ks = 0; ks < 2; ++ks) {
        xhf[ks] = *(const s16x8*)&Xh[ech][xrow][lg * 8 + ks * 32];
        xlf[ks] = *(const s16x8*)&Xl[ech][xrow][lg * 8 + ks * 32];
      }
      f32x4 acc[4];
#pragma unroll
      for (int ct = 0; ct < 4; ++ct) {
        acc[ct] = (f32x4){ebias[ct], ebias[ct], ebias[ct], ebias[ct]};
#pragma unroll
        for (int ks = 0; ks < 2; ++ks) {
          acc[ct] = __builtin_amdgcn_mfma_f32_16x16x32_bf16(
              xhf[ks], wfh[ct * 2 + ks], acc[ct], 0, 0, 0);
          acc[ct] = __builtin_amdgcn_mfma_f32_16x16x32_bf16(
              xlf[ks], wfh[ct * 2 + ks], acc[ct], 0, 0, 0);
          acc[ct] = __builtin_amdgcn_mfma_f32_16x16x32_bf16(
              xhf[ks], wfl[ct * 2 + ks], acc[ct], 0, 0, 0);
        }
      }
      const u64 emask = lev[ech][hop];
#pragma unroll
      for (int r = 0; r < 4; ++r) {
        const int row = eslab + lg * 4 + r;
        if ((emask >> row) & 1ull) {
#pragma unroll
          for (int ct = 0; ct < 4; ++ct)
            Sb[ech][row][ct * 16 + ln15] = fmaxf(acc[ct][r], 0.f);
        }
      }
    }
    __syncthreads();
  }

  // final layer 3 write
  {
#pragma unroll
    for (int u = 0; u < 2; ++u) {
      const float4 a = *(const float4*)&Sb[0][r8][cc8 + 4 * u];
      const float4 b = *(const float4*)&Sb[1][r8][cc8 + 4 * u];
      *(float4*)&out[(size_t)(nb + r8) * 256 + 192 + cc8 + 4 * u] =
          make_float4(a.x + b.x, a.y + b.y, a.z + b.z, a.w + b.w);
    }
  }
}

extern "C" void kernel_launch(void* const* d_in, const int* in_sizes, int n_in,
                              void* d_out, int out_size, void* d_ws, size_t ws_size,
                              hipStream_t stream) {
  const float* adj       = (const float*)d_in[0];
  const float* feat_node = (const float*)d_in[1];
  const int*   idx       = (const int*)d_in[2];
  const int*   head_ids  = (const int*)d_in[3];
  const int*   tail_ids  = (const int*)d_in[4];
  // d_in[5] = graph_indices (implied by block structure, unused)
  const float* transform = (const float*)d_in[6];
  const float* embed     = (const float*)d_in[7];
  const float* w1v    = (const float*)d_in[8];
  const float* b1v    = (const float*)d_in[9];
  const float* w2v    = (const float*)d_in[10];
  const float* b2v    = (const float*)d_in[11];
  const float* gamma1 = (const float*)d_in[12];
  const float* beta1  = (const float*)d_in[13];
  const float* gamma2 = (const float*)d_in[14];
  const float* beta2  = (const float*)d_in[15];

  lagat_kernel<<<64, 512, 0, stream>>>(adj, feat_node, idx, head_ids, tail_ids,
      transform, embed, w1v, b1v, w2v, b2v, gamma1, beta1, gamma2, beta2,
      (float*)d_out);
}

// Round 10
// 38.305 us; speedup vs baseline: 1.0291x; 1.0291x over previous
//
#include <hip/hip_runtime.h>

#define LD 68  // fp32 LDS row stride: 272B = 17x16B
#define XP 72  // bf16 X row pitch: 144B = 9x16B, conflict-free frag reads

typedef float f32x4 __attribute__((ext_vector_type(4)));
typedef short s16x8 __attribute__((ext_vector_type(8)));

__device__ __forceinline__ unsigned short f2bf(float f) {
  union { float f; unsigned int u; } v; v.f = f;
  const unsigned int r = (v.u + 0x7fffu + ((v.u >> 16) & 1u)) >> 16;
  return (unsigned short)r;
}
__device__ __forceinline__ float bf2f(unsigned short h) {
  union { unsigned int u; float f; } v; v.u = ((unsigned int)h) << 16;
  return v.f;
}

__global__ __launch_bounds__(512) void lagat_kernel(
    const float* __restrict__ adj,
    const float* __restrict__ feat_node,
    const int* __restrict__ idx,
    const int* __restrict__ head_ids,
    const int* __restrict__ tail_ids,
    const float* __restrict__ transform,
    const float* __restrict__ embed,
    const float* __restrict__ w1, const float* __restrict__ b1,
    const float* __restrict__ w2, const float* __restrict__ b2,
    const float* __restrict__ gamma1, const float* __restrict__ beta1,
    const float* __restrict__ gamma2, const float* __restrict__ beta2,
    float* __restrict__ out)
{
  __shared__ __align__(16) float Ab[64][LD];     // adjacency (0/1, symmetric)
  __shared__ __align__(16) float featb[64][LD];  // transformed features
  __shared__ __align__(16) float Sb[2][64][LD];  // head/tail running state
  __shared__ __align__(16) float Ib[64][LD];     // init_feat scratch
  __shared__ __align__(16) unsigned short Xh[2][64][XP];  // X hi (bf16)
  __shared__ __align__(16) unsigned short Xl[2][64][XP];  // X lo (bf16)
  __shared__ float prm[2][3][64];                // gamma, beta, bias per chain
  __shared__ float reach[2][3][64];              // BFS reach (0/1)
  __shared__ float degs[64];
  __shared__ float corr[2][64];

  const int g = blockIdx.x, tid = threadIdx.x, nb = g * 64;

  // ---- P0: global -> LDS ----
  {
    const int r = tid >> 3, c8 = (tid & 7) * 8;
    const float4* asrc = (const float4*)&adj[(size_t)(nb + r) * 4096 + nb + c8];
    *(float4*)&Ab[r][c8]     = asrc[0];
    *(float4*)&Ab[r][c8 + 4] = asrc[1];
    if (c8 < 32) {
      const float4* fs = (const float4*)&feat_node[(size_t)(nb + r) * 32 + c8];
      *(float4*)&Ib[r][c8]     = fs[0];
      *(float4*)&Ib[r][c8 + 4] = fs[1];
    } else {
      const float4* es = (const float4*)&embed[(size_t)idx[nb + r] * 32 + (c8 - 32)];
      *(float4*)&Ib[r][c8]     = es[0];
      *(float4*)&Ib[r][c8 + 4] = es[1];
    }
  }
  if (tid < 384) {
    const int a = tid >> 6, h = tid & 63;
    const float* s6 = (a == 0) ? gamma1 : (a == 1) ? beta1 : (a == 2) ? b1
                    : (a == 3) ? gamma2 : (a == 4) ? beta2 : b2;
    prm[a / 3][a % 3][h] = s6[h];
  }
  __syncthreads();

  const int hl = head_ids[g] - nb, tl = tail_ids[g] - nb;

  // ---- E-phase wave mapping + W fragments from global (once) ----
  const int wv = tid >> 6, lane = tid & 63;
  const int ech = wv >> 2, eslab = (wv & 3) * 16;
  const int ln15 = lane & 15, lg = lane >> 4;
  s16x8 wfh[8], wfl[8];   // [ct*2+ks], hi/lo bf16 B-frags, persist in VGPRs
  float ebias[4], qe[4];
  {
    const float* Wg = ech ? w2 : w1;
#pragma unroll
    for (int ct = 0; ct < 4; ++ct) {
#pragma unroll
      for (int ks = 0; ks < 2; ++ks) {
        s16x8 h, lo;
#pragma unroll
        for (int j = 0; j < 8; ++j) {
          const float w = Wg[(size_t)(ks * 32 + lg * 8 + j) * 64 + ct * 16 + ln15];
          const unsigned short hu = f2bf(w);
          h[j] = (short)hu;
          lo[j] = (short)f2bf(w - bf2f(hu));
        }
        wfh[ct * 2 + ks] = h;
        wfl[ct * 2 + ks] = lo;
      }
    }
  }

  // ---- P1: reach0/1 + degs (subset) || transform GEMM 2x4-tiled (all) ----
  if (tid < 128) {
    const int c = tid >> 6, j = tid & 63;
    const int root = c ? tl : hl;
    reach[c][0][j] = (j == root) ? 1.f : 0.f;
    reach[c][1][j] = (j == root || Ab[root][j] != 0.f) ? 1.f : 0.f;
  } else if (tid < 192) {
    const int i = tid & 63;
    float s = 0.f;
    for (int k = 0; k < 64; ++k) s += Ab[i][k];
    degs[i] = s;
  }
  {
    const int c0g = (tid & 15) * 4, r0g = (tid >> 4) * 2;
    float a0c[4] = {}, a1c[4] = {};
    for (int k = 0; k < 64; ++k) {
      const float4 t4 = *(const float4*)&transform[(size_t)k * 64 + c0g];
      const float a0 = Ib[r0g][k], a1 = Ib[r0g + 1][k];
      a0c[0] = fmaf(a0, t4.x, a0c[0]); a0c[1] = fmaf(a0, t4.y, a0c[1]);
      a0c[2] = fmaf(a0, t4.z, a0c[2]); a0c[3] = fmaf(a0, t4.w, a0c[3]);
      a1c[0] = fmaf(a1, t4.x, a1c[0]); a1c[1] = fmaf(a1, t4.y, a1c[1]);
      a1c[2] = fmaf(a1, t4.z, a1c[2]); a1c[3] = fmaf(a1, t4.w, a1c[3]);
    }
    *(float4*)&featb[r0g][c0g]     = make_float4(a0c[0], a0c[1], a0c[2], a0c[3]);
    *(float4*)&featb[r0g + 1][c0g] = make_float4(a1c[0], a1c[1], a1c[2], a1c[3]);
  }
  __syncthreads();

  // ---- P2: reach2 (subset) + corr init + S init + layer-0 write ----
  if (tid < 128) {
    const int c = tid >> 6, j = tid & 63;
    const int root = c ? tl : hl;
    float v = (j == root) ? 1.f : 0.f;
    for (int k = 0; k < 64; ++k)
      if (reach[c][1][k] != 0.f && Ab[k][j] != 0.f) v = 1.f;
    reach[c][2][j] = v;
    // corr init: |q . feat[i]|  (S == feat at hop start)
    const int qr = c ? hl : tl;
    float s = 0.f;
    for (int l = 0; l < 64; ++l) s = fmaf(featb[qr][l], featb[j][l], s);
    corr[c][j] = fabsf(s);
  }
  {
    const int r = tid >> 3, c8 = (tid & 7) * 8;
#pragma unroll
    for (int u = 0; u < 2; ++u) {
      const float4 v = *(const float4*)&featb[r][c8 + 4 * u];
      *(float4*)&Sb[0][r][c8 + 4 * u] = v;
      *(float4*)&Sb[1][r][c8 + 4 * u] = v;
      *(float4*)&out[(size_t)(nb + r) * 256 + c8 + 4 * u] = v;
    }
  }
  {
    const int qrE = ech ? hl : tl;
#pragma unroll
    for (int ct = 0; ct < 4; ++ct) {
      ebias[ct] = prm[ech][2][ct * 16 + ln15];
      qe[ct] = featb[qrE][ct * 16 + ln15];
    }
  }
  __syncthreads();

  // ---- hop-loop mappings + register preloads (loop-invariant) ----
  const int ch = tid >> 8, t = tid & 255;
  const int c0 = (t & 15) * 4, r0 = (t >> 4) * 4;  // 4x4 tile (B/D)
  const int r8 = tid >> 3, cc8 = (tid & 7) * 8;    // layer-write map

  float dn[4], ga[4], be[4];
  float4 ft[4];
#pragma unroll
  for (int m = 0; m < 4; ++m) {
    dn[m] = 1.f / (degs[r0 + m] + 1e-8f);
    ft[m] = *(const float4*)&featb[r0 + m][c0];
  }
#pragma unroll
  for (int c = 0; c < 4; ++c) {
    ga[c] = prm[ch][0][c0 + c];
    be[c] = prm[ch][1][c0 + c];
  }

  for (int hop = 2; hop >= 0; --hop) {
    // deferred layer write (L = 2-hop); pure read of Sb, no barrier needed
    if (hop != 2) {
      const int L = 2 - hop;
#pragma unroll
      for (int u = 0; u < 2; ++u) {
        const float4 a = *(const float4*)&Sb[0][r8][cc8 + 4 * u];
        const float4 b = *(const float4*)&Sb[1][r8][cc8 + 4 * u];
        *(float4*)&out[(size_t)(nb + r8) * 256 + (size_t)L * 64 + cc8 + 4 * u] =
            make_float4(a.x + b.x, a.y + b.y, a.z + b.z, a.w + b.w);
      }
    }

    // B+C+D fused, 4x4 register tile; D writes X as bf16 hi/lo
    {
      float acc[4][4] = {};
      for (int j = 0; j < 64; ++j) {
        const float cj = corr[ch][j];
        const float4 a4 = *(const float4*)&Ab[j][r0];      // symmetric adj
        const float4 s4 = *(const float4*)&Sb[ch][j][c0];
        const float w0 = a4.x * cj, w1_ = a4.y * cj;
        const float w2_ = a4.z * cj, w3_ = a4.w * cj;
        acc[0][0] = fmaf(w0, s4.x, acc[0][0]); acc[0][1] = fmaf(w0, s4.y, acc[0][1]);
        acc[0][2] = fmaf(w0, s4.z, acc[0][2]); acc[0][3] = fmaf(w0, s4.w, acc[0][3]);
        acc[1][0] = fmaf(w1_, s4.x, acc[1][0]); acc[1][1] = fmaf(w1_, s4.y, acc[1][1]);
        acc[1][2] = fmaf(w1_, s4.z, acc[1][2]); acc[1][3] = fmaf(w1_, s4.w, acc[1][3]);
        acc[2][0] = fmaf(w2_, s4.x, acc[2][0]); acc[2][1] = fmaf(w2_, s4.y, acc[2][1]);
        acc[2][2] = fmaf(w2_, s4.z, acc[2][2]); acc[2][3] = fmaf(w2_, s4.w, acc[2][3]);
        acc[3][0] = fmaf(w3_, s4.x, acc[3][0]); acc[3][1] = fmaf(w3_, s4.y, acc[3][1]);
        acc[3][2] = fmaf(w3_, s4.z, acc[3][2]); acc[3][3] = fmaf(w3_, s4.w, acc[3][3]);
      }
      float x[4][4], sm[4], s2[4];
#pragma unroll
      for (int m = 0; m < 4; ++m) {
        float smm = 0.f, s2m = 0.f;
#pragma unroll
        for (int c = 0; c < 4; ++c) {
          float z = acc[m][c];
          z = (z > 0.f) ? z : 0.01f * z;   // leaky_relu slope 0.01
          z *= dn[m];
          x[m][c] = z; smm += z; s2m = fmaf(z, z, s2m);
        }
        sm[m] = smm; s2[m] = s2m;
      }
#pragma unroll
      for (int mask = 1; mask < 16; mask <<= 1) {
#pragma unroll
        for (int m = 0; m < 4; ++m) {
          sm[m] += __shfl_xor(sm[m], mask);
          s2[m] += __shfl_xor(s2[m], mask);
        }
      }
#pragma unroll
      for (int m = 0; m < 4; ++m) {
        const float mu = sm[m] * 0.015625f;
        const float var = fmaxf(s2[m] * 0.015625f - mu * mu, 0.f);
        const float rstd = rsqrtf(var + 1e-5f);
        const float f = reach[ch][hop][r0 + m];
        float xv[4];
        xv[0] = fmaf(f, ft[m].x, ga[0] * (x[m][0] - mu) * rstd + be[0]);
        xv[1] = fmaf(f, ft[m].y, ga[1] * (x[m][1] - mu) * rstd + be[1]);
        xv[2] = fmaf(f, ft[m].z, ga[2] * (x[m][2] - mu) * rstd + be[2]);
        xv[3] = fmaf(f, ft[m].w, ga[3] * (x[m][3] - mu) * rstd + be[3]);
        ushort4 h4, l4;
        h4.x = f2bf(xv[0]); l4.x = f2bf(xv[0] - bf2f(h4.x));
        h4.y = f2bf(xv[1]); l4.y = f2bf(xv[1] - bf2f(h4.y));
        h4.z = f2bf(xv[2]); l4.z = f2bf(xv[2] - bf2f(h4.z));
        h4.w = f2bf(xv[3]); l4.w = f2bf(xv[3] - bf2f(h4.w));
        *(ushort4*)&Xh[ch][r0 + m][c0] = h4;
        *(ushort4*)&Xl[ch][r0 + m][c0] = l4;
      }
    }
    __syncthreads();

    // E (MFMA): S[i] = f ? relu(X[i] @ W + b) : S[i]; corr update fused
    {
      s16x8 xhf[2], xlf[2];
      const int xrow = eslab + ln15;
#pragma unroll
      for (int ks = 0; ks < 2; ++ks) {
        xhf[ks] = *(const s16x8*)&Xh[ech][xrow][lg * 8 + ks * 32];
        xlf[ks] = *(const s16x8*)&Xl[ech][xrow][lg * 8 + ks * 32];
      }
      f32x4 acc[4];
#pragma unroll
      for (int ct = 0; ct < 4; ++ct) {
        acc[ct] = (f32x4){ebias[ct], ebias[ct], ebias[ct], ebias[ct]};
#pragma unroll
        for (int ks = 0; ks < 2; ++ks) {
          acc[ct] = __builtin_amdgcn_mfma_f32_16x16x32_bf16(
              xhf[ks], wfh[ct * 2 + ks], acc[ct], 0, 0, 0);
          acc[ct] = __builtin_amdgcn_mfma_f32_16x16x32_bf16(
              xlf[ks], wfh[ct * 2 + ks], acc[ct], 0, 0, 0);
          acc[ct] = __builtin_amdgcn_mfma_f32_16x16x32_bf16(
              xhf[ks], wfl[ct * 2 + ks], acc[ct], 0, 0, 0);
        }
      }
      float fm[4];
#pragma unroll
      for (int r = 0; r < 4; ++r)
        fm[r] = reach[ech][hop][eslab + lg * 4 + r];
#pragma unroll
      for (int r = 0; r < 4; ++r) {
        const int row = eslab + lg * 4 + r;
        const float sv0 = fmaxf(acc[0][r], 0.f), sv1 = fmaxf(acc[1][r], 0.f);
        const float sv2 = fmaxf(acc[2][r], 0.f), sv3 = fmaxf(acc[3][r], 0.f);
        // corr for the would-be-updated row: |q . S_new[row]|
        float v = sv0 * qe[0] + sv1 * qe[1] + sv2 * qe[2] + sv3 * qe[3];
        v += __shfl_xor(v, 1); v += __shfl_xor(v, 2);
        v += __shfl_xor(v, 4); v += __shfl_xor(v, 8);
        if (fm[r] != 0.f) {
          Sb[ech][row][ln15]      = sv0;
          Sb[ech][row][16 + ln15] = sv1;
          Sb[ech][row][32 + ln15] = sv2;
          Sb[ech][row][48 + ln15] = sv3;
          if (ln15 == 0) corr[ech][row] = fabsf(v);
        }
      }
    }
    __syncthreads();
  }

  // final layer 3 write
  {
#pragma unroll
    for (int u = 0; u < 2; ++u) {
      const float4 a = *(const float4*)&Sb[0][r8][cc8 + 4 * u];
      const float4 b = *(const float4*)&Sb[1][r8][cc8 + 4 * u];
      *(float4*)&out[(size_t)(nb + r8) * 256 + 192 + cc8 + 4 * u] =
          make_float4(a.x + b.x, a.y + b.y, a.z + b.z, a.w + b.w);
    }
  }
}

extern "C" void kernel_launch(void* const* d_in, const int* in_sizes, int n_in,
                              void* d_out, int out_size, void* d_ws, size_t ws_size,
                              hipStream_t stream) {
  const float* adj       = (const float*)d_in[0];
  const float* feat_node = (const float*)d_in[1];
  const int*   idx       = (const int*)d_in[2];
  const int*   head_ids  = (const int*)d_in[3];
  const int*   tail_ids  = (const int*)d_in[4];
  // d_in[5] = graph_indices (implied by block structure, unused)
  const float* transform = (const float*)d_in[6];
  const float* embed     = (const float*)d_in[7];
  const float* w1v    = (const float*)d_in[8];
  const float* b1v    = (const float*)d_in[9];
  const float* w2v    = (const float*)d_in[10];
  const float* b2v    = (const float*)d_in[11];
  const float* gamma1 = (const float*)d_in[12];
  const float* beta1  = (const float*)d_in[13];
  const float* gamma2 = (const float*)d_in[14];
  const float* beta2  = (const float*)d_in[15];

  lagat_kernel<<<64, 512, 0, stream>>>(adj, feat_node, idx, head_ids, tail_ids,
      transform, embed, w1v, b1v, w2v, b2v, gamma1, beta1, gamma2, beta2,
      (float*)d_out);
}

// Round 11
// 27.124 us; speedup vs baseline: 1.4533x; 1.4122x over previous
//
#include <hip/hip_runtime.h>

#define LD 68  // fp32 LDS row stride: 272B
#define XP 72  // bf16 row pitch (ushorts): 144B

typedef float f32x4 __attribute__((ext_vector_type(4)));
typedef short s16x8 __attribute__((ext_vector_type(8)));

__device__ __forceinline__ unsigned short f2bf(float f) {
  union { float f; unsigned int u; } v; v.f = f;
  const unsigned int r = (v.u + 0x7fffu + ((v.u >> 16) & 1u)) >> 16;
  return (unsigned short)r;
}
__device__ __forceinline__ float bf2f(unsigned short h) {
  union { unsigned int u; float f; } v; v.u = ((unsigned int)h) << 16;
  return v.f;
}

__global__ __launch_bounds__(512) void lagat_kernel(
    const float* __restrict__ adj,
    const float* __restrict__ feat_node,
    const int* __restrict__ idx,
    const int* __restrict__ head_ids,
    const int* __restrict__ tail_ids,
    const float* __restrict__ transform,
    const float* __restrict__ embed,
    const float* __restrict__ w1, const float* __restrict__ b1,
    const float* __restrict__ w2, const float* __restrict__ b2,
    const float* __restrict__ gamma1, const float* __restrict__ beta1,
    const float* __restrict__ gamma2, const float* __restrict__ beta2,
    float* __restrict__ out)
{
  // hop-loop arrays; Ab/Ib (setup-only) alias Xh/CSTh regions
  __shared__ __align__(16) unsigned short Xh[2][64][XP];   // X hi (bf16)
  __shared__ __align__(16) unsigned short Xl[2][64][XP];   // X lo
  __shared__ __align__(16) unsigned short CSTh[2][64][XP]; // (corr*S)^T hi
  __shared__ __align__(16) unsigned short CSTl[2][64][XP]; // (corr*S)^T lo
  __shared__ __align__(16) float Sb[2][64][LD];            // running state
  __shared__ __align__(16) float featb[64][LD];            // features
  __shared__ __align__(16) float prm[2][3][64];            // gamma,beta,bias
  __shared__ float reach[2][3][64];
  __shared__ float degs[64];
  __shared__ float corr[2][64];                            // init only

  float (*Ab)[LD] = reinterpret_cast<float(*)[LD]>(&Xh[0][0][0]);   // 17.4KB in 18.4KB
  float (*Ib)[LD] = reinterpret_cast<float(*)[LD]>(&CSTh[0][0][0]);

  const int g = blockIdx.x, tid = threadIdx.x, nb = g * 64;
  const int wv = tid >> 6, lane = tid & 63;
  const int ech = wv >> 2, eslab = (wv & 3) * 16;
  const int ln15 = lane & 15, lg = lane >> 4, lg4 = lg * 4;
  const int iNode = eslab + ln15;

  // ---- P0: global -> LDS ----
  {
    const int r = tid >> 3, c8 = (tid & 7) * 8;
    const float4* asrc = (const float4*)&adj[(size_t)(nb + r) * 4096 + nb + c8];
    *(float4*)&Ab[r][c8]     = asrc[0];
    *(float4*)&Ab[r][c8 + 4] = asrc[1];
    if (c8 < 32) {
      const float4* fs = (const float4*)&feat_node[(size_t)(nb + r) * 32 + c8];
      *(float4*)&Ib[r][c8]     = fs[0];
      *(float4*)&Ib[r][c8 + 4] = fs[1];
    } else {
      const float4* es = (const float4*)&embed[(size_t)idx[nb + r] * 32 + (c8 - 32)];
      *(float4*)&Ib[r][c8]     = es[0];
      *(float4*)&Ib[r][c8 + 4] = es[1];
    }
  }
  if (tid < 384) {
    const int a = tid >> 6, h = tid & 63;
    const float* s6 = (a == 0) ? gamma1 : (a == 1) ? beta1 : (a == 2) ? b1
                    : (a == 3) ? gamma2 : (a == 4) ? beta2 : b2;
    prm[a / 3][a % 3][h] = s6[h];
  }

  // W^T fragments from global (same index map as A- or B-frag on gfx950)
  s16x8 wfh[8], wfl[8];
  {
    const float* Wg = ech ? w2 : w1;
#pragma unroll
    for (int ct = 0; ct < 4; ++ct)
#pragma unroll
      for (int ks = 0; ks < 2; ++ks) {
        s16x8 h, lo;
#pragma unroll
        for (int j = 0; j < 8; ++j) {
          const float w = Wg[(size_t)(ks * 32 + lg * 8 + j) * 64 + ct * 16 + ln15];
          const unsigned short hu = f2bf(w);
          h[j] = (short)hu;
          lo[j] = (short)f2bf(w - bf2f(hu));
        }
        wfh[ct * 2 + ks] = h;
        wfl[ct * 2 + ks] = lo;
      }
  }
  __syncthreads();

  const int hl = head_ids[g] - nb, tl = tail_ids[g] - nb;

  // ---- P1: reach0/1 + degs || transform GEMM (Ib -> featb) ----
  if (tid < 128) {
    const int c = tid >> 6, j = tid & 63;
    const int root = c ? tl : hl;
    reach[c][0][j] = (j == root) ? 1.f : 0.f;
    reach[c][1][j] = (j == root || Ab[root][j] != 0.f) ? 1.f : 0.f;
  } else if (tid < 192) {
    const int i = tid & 63;
    float s = 0.f;
    for (int k = 0; k < 64; ++k) s += Ab[i][k];
    degs[i] = s;
  }
  {
    const int c0g = (tid & 15) * 4, r0g = (tid >> 4) * 2;
    float a0c[4] = {}, a1c[4] = {};
    for (int k = 0; k < 64; ++k) {
      const float4 t4 = *(const float4*)&transform[(size_t)k * 64 + c0g];
      const float a0 = Ib[r0g][k], a1 = Ib[r0g + 1][k];
      a0c[0] = fmaf(a0, t4.x, a0c[0]); a0c[1] = fmaf(a0, t4.y, a0c[1]);
      a0c[2] = fmaf(a0, t4.z, a0c[2]); a0c[3] = fmaf(a0, t4.w, a0c[3]);
      a1c[0] = fmaf(a1, t4.x, a1c[0]); a1c[1] = fmaf(a1, t4.y, a1c[1]);
      a1c[2] = fmaf(a1, t4.z, a1c[2]); a1c[3] = fmaf(a1, t4.w, a1c[3]);
    }
    *(float4*)&featb[r0g][c0g]     = make_float4(a0c[0], a0c[1], a0c[2], a0c[3]);
    *(float4*)&featb[r0g + 1][c0g] = make_float4(a1c[0], a1c[1], a1c[2], a1c[3]);
  }
  __syncthreads();

  // ---- P2: reach2 + corr init (128 thr) ; S init + layer-0 (all) ----
  if (tid < 128) {
    const int c = tid >> 6, j = tid & 63;
    const int root = c ? tl : hl;
    float v = (j == root) ? 1.f : 0.f;
    for (int k = 0; k < 64; ++k)
      if (reach[c][1][k] != 0.f && Ab[k][j] != 0.f) v = 1.f;
    reach[c][2][j] = v;
    const int qr = c ? hl : tl;
    float s = 0.f;
    for (int l4 = 0; l4 < 64; l4 += 4) {
      const float4 q4 = *(const float4*)&featb[qr][l4];
      const float4 f4 = *(const float4*)&featb[j][l4];
      s = fmaf(q4.x, f4.x, s); s = fmaf(q4.y, f4.y, s);
      s = fmaf(q4.z, f4.z, s); s = fmaf(q4.w, f4.w, s);
    }
    corr[c][j] = fabsf(s);
  }
  {
    const int r = tid >> 3, c8 = (tid & 7) * 8;
#pragma unroll
    for (int u = 0; u < 2; ++u) {
      const float4 v = *(const float4*)&featb[r][c8 + 4 * u];
      *(float4*)&Sb[0][r][c8 + 4 * u] = v;
      *(float4*)&Sb[1][r][c8 + 4 * u] = v;
      *(float4*)&out[(size_t)(nb + r) * 256 + c8 + 4 * u] = v;
    }
  }
  // adjacency B-frags (symmetric A: read row iNode) + per-lane preloads
  s16x8 afr[2];
#pragma unroll
  for (int ks = 0; ks < 2; ++ks) {
    s16x8 a;
#pragma unroll
    for (int j = 0; j < 8; ++j)
      a[j] = (short)f2bf(Ab[iNode][ks * 32 + lg * 8 + j]);
    afr[ks] = a;
  }
  const float dnv = 1.f / (degs[iNode] + 1e-8f);
  f32x4 ft4[4];
#pragma unroll
  for (int ct = 0; ct < 4; ++ct)
    ft4[ct] = *(const f32x4*)&featb[iNode][ct * 16 + lg4];
  __syncthreads();

  // ---- P2b: CST init = corr_init[j] * feat[j][c], bf16 hi/lo ----
  {
    const int ch2 = tid >> 8, t = tid & 255;
    const int c = t >> 2, j0 = (t & 3) * 16;
#pragma unroll
    for (int half = 0; half < 2; ++half) {
      s16x8 hh, ll;
#pragma unroll
      for (int m = 0; m < 8; ++m) {
        const int j = j0 + half * 8 + m;
        const float cs = corr[ch2][j] * featb[j][c];
        const unsigned short h = f2bf(cs);
        hh[m] = (short)h;
        ll[m] = (short)f2bf(cs - bf2f(h));
      }
      *(s16x8*)&CSTh[ch2][c][j0 + half * 8] = hh;
      *(s16x8*)&CSTl[ch2][c][j0 + half * 8] = ll;
    }
  }
  __syncthreads();

  const int r8 = tid >> 3, cc8 = (tid & 7) * 8;   // layer-write map
  const int qrowE = ech ? hl : tl;

  for (int hop = 2; hop >= 0; --hop) {
    // deferred layer write (L = 2-hop); reads Sb (synced by prev barrier)
    if (hop != 2) {
      const int L = 2 - hop;
#pragma unroll
      for (int u = 0; u < 2; ++u) {
        const float4 a = *(const float4*)&Sb[0][r8][cc8 + 4 * u];
        const float4 b = *(const float4*)&Sb[1][r8][cc8 + 4 * u];
        *(float4*)&out[(size_t)(nb + r8) * 256 + (size_t)L * 64 + cc8 + 4 * u] =
            make_float4(a.x + b.x, a.y + b.y, a.z + b.z, a.w + b.w);
      }
    }

    // B (MFMA, swapped): up^T[c][i] = sum_j CST[c][j] * A[j][i]; then C+D
    {
      f32x4 acc[4] = {{0,0,0,0},{0,0,0,0},{0,0,0,0},{0,0,0,0}};
#pragma unroll
      for (int ct = 0; ct < 4; ++ct)
#pragma unroll
        for (int ks = 0; ks < 2; ++ks) {
          const s16x8 ah = *(const s16x8*)&CSTh[ech][ct * 16 + ln15][ks * 32 + lg * 8];
          const s16x8 al = *(const s16x8*)&CSTl[ech][ct * 16 + ln15][ks * 32 + lg * 8];
          acc[ct] = __builtin_amdgcn_mfma_f32_16x16x32_bf16(ah, afr[ks], acc[ct], 0, 0, 0);
          acc[ct] = __builtin_amdgcn_mfma_f32_16x16x32_bf16(al, afr[ks], acc[ct], 0, 0, 0);
        }
      float x[4][4], smm = 0.f, s2m = 0.f;
#pragma unroll
      for (int ct = 0; ct < 4; ++ct)
#pragma unroll
        for (int r = 0; r < 4; ++r) {
          float z = acc[ct][r];
          z = (z > 0.f) ? z : 0.01f * z;   // leaky_relu slope 0.01
          z *= dnv;
          x[ct][r] = z; smm += z; s2m = fmaf(z, z, s2m);
        }
      smm += __shfl_xor(smm, 16); smm += __shfl_xor(smm, 32);
      s2m += __shfl_xor(s2m, 16); s2m += __shfl_xor(s2m, 32);
      const float mu = smm * 0.015625f;
      const float var = fmaxf(s2m * 0.015625f - mu * mu, 0.f);
      const float rstd = rsqrtf(var + 1e-5f);
      const float fE = reach[ech][hop][iNode];
#pragma unroll
      for (int ct = 0; ct < 4; ++ct) {
        const f32x4 ga4 = *(const f32x4*)&prm[ech][0][ct * 16 + lg4];
        const f32x4 be4 = *(const f32x4*)&prm[ech][1][ct * 16 + lg4];
        ushort4 h4, l4;
        {
          const float xv = fmaf(fE, ft4[ct][0], ga4[0] * (x[ct][0] - mu) * rstd + be4[0]);
          h4.x = f2bf(xv); l4.x = f2bf(xv - bf2f(h4.x));
        }
        {
          const float xv = fmaf(fE, ft4[ct][1], ga4[1] * (x[ct][1] - mu) * rstd + be4[1]);
          h4.y = f2bf(xv); l4.y = f2bf(xv - bf2f(h4.y));
        }
        {
          const float xv = fmaf(fE, ft4[ct][2], ga4[2] * (x[ct][2] - mu) * rstd + be4[2]);
          h4.z = f2bf(xv); l4.z = f2bf(xv - bf2f(h4.z));
        }
        {
          const float xv = fmaf(fE, ft4[ct][3], ga4[3] * (x[ct][3] - mu) * rstd + be4[3]);
          h4.w = f2bf(xv); l4.w = f2bf(xv - bf2f(h4.w));
        }
        *(ushort4*)&Xh[ech][iNode][ct * 16 + lg4] = h4;
        *(ushort4*)&Xl[ech][iNode][ct * 16 + lg4] = l4;
      }
    }
    __syncthreads();

    // E (MFMA, swapped): (X@W)^T[c][i]; S/CST update fused
    {
      s16x8 xh2[2], xl2[2];
#pragma unroll
      for (int ks = 0; ks < 2; ++ks) {
        xh2[ks] = *(const s16x8*)&Xh[ech][iNode][ks * 32 + lg * 8];
        xl2[ks] = *(const s16x8*)&Xl[ech][iNode][ks * 32 + lg * 8];
      }
      f32x4 acc[4];
#pragma unroll
      for (int ct = 0; ct < 4; ++ct) {
        acc[ct] = *(const f32x4*)&prm[ech][2][ct * 16 + lg4];  // bias
#pragma unroll
        for (int ks = 0; ks < 2; ++ks) {
          acc[ct] = __builtin_amdgcn_mfma_f32_16x16x32_bf16(wfh[ct*2+ks], xh2[ks], acc[ct], 0, 0, 0);
          acc[ct] = __builtin_amdgcn_mfma_f32_16x16x32_bf16(wfh[ct*2+ks], xl2[ks], acc[ct], 0, 0, 0);
          acc[ct] = __builtin_amdgcn_mfma_f32_16x16x32_bf16(wfl[ct*2+ks], xh2[ks], acc[ct], 0, 0, 0);
        }
      }
      float s[4][4], v = 0.f;
#pragma unroll
      for (int ct = 0; ct < 4; ++ct) {
        const f32x4 qe4 = *(const f32x4*)&featb[qrowE][ct * 16 + lg4];
#pragma unroll
        for (int r = 0; r < 4; ++r) {
          const float sv = fmaxf(acc[ct][r], 0.f);
          s[ct][r] = sv;
          v = fmaf(qe4[r], sv, v);
        }
      }
      v += __shfl_xor(v, 16); v += __shfl_xor(v, 32);
      const float vc = fabsf(v);
      const float fE = reach[ech][hop][iNode];
      if (fE != 0.f) {
#pragma unroll
        for (int ct = 0; ct < 4; ++ct) {
          *(float4*)&Sb[ech][iNode][ct * 16 + lg4] =
              make_float4(s[ct][0], s[ct][1], s[ct][2], s[ct][3]);
#pragma unroll
          for (int r = 0; r < 4; ++r) {
            const float cs = vc * s[ct][r];
            const unsigned short h = f2bf(cs);
            CSTh[ech][ct * 16 + lg4 + r][iNode] = h;
            CSTl[ech][ct * 16 + lg4 + r][iNode] = f2bf(cs - bf2f(h));
          }
        }
      }
    }
    __syncthreads();
  }

  // final layer 3 write
  {
#pragma unroll
    for (int u = 0; u < 2; ++u) {
      const float4 a = *(const float4*)&Sb[0][r8][cc8 + 4 * u];
      const float4 b = *(const float4*)&Sb[1][r8][cc8 + 4 * u];
      *(float4*)&out[(size_t)(nb + r8) * 256 + 192 + cc8 + 4 * u] =
          make_float4(a.x + b.x, a.y + b.y, a.z + b.z, a.w + b.w);
    }
  }
}

extern "C" void kernel_launch(void* const* d_in, const int* in_sizes, int n_in,
                              void* d_out, int out_size, void* d_ws, size_t ws_size,
                              hipStream_t stream) {
  const float* adj       = (const float*)d_in[0];
  const float* feat_node = (const float*)d_in[1];
  const int*   idx       = (const int*)d_in[2];
  const int*   head_ids  = (const int*)d_in[3];
  const int*   tail_ids  = (const int*)d_in[4];
  // d_in[5] = graph_indices (implied by block structure, unused)
  const float* transform = (const float*)d_in[6];
  const float* embed     = (const float*)d_in[7];
  const float* w1v    = (const float*)d_in[8];
  const float* b1v    = (const float*)d_in[9];
  const float* w2v    = (const float*)d_in[10];
  const float* b2v    = (const float*)d_in[11];
  const float* gamma1 = (const float*)d_in[12];
  const float* beta1  = (const float*)d_in[13];
  const float* gamma2 = (const float*)d_in[14];
  const float* beta2  = (const float*)d_in[15];

  lagat_kernel<<<64, 512, 0, stream>>>(adj, feat_node, idx, head_ids, tail_ids,
      transform, embed, w1v, b1v, w2v, b2v, gamma1, beta1, gamma2, beta2,
      (float*)d_out);
}

// Round 12
// 24.451 us; speedup vs baseline: 1.6122x; 1.1093x over previous
//
#include <hip/hip_runtime.h>

#define LD 68  // fp32 LDS row stride: 272B
#define XP 72  // bf16 row pitch (ushorts): 144B

typedef float f32x4 __attribute__((ext_vector_type(4)));
typedef short s16x8 __attribute__((ext_vector_type(8)));

__device__ __forceinline__ unsigned short f2bf(float f) {
  union { float f; unsigned int u; } v; v.f = f;
  const unsigned int r = (v.u + 0x7fffu + ((v.u >> 16) & 1u)) >> 16;
  return (unsigned short)r;
}
__device__ __forceinline__ float bf2f(unsigned short h) {
  union { unsigned int u; float f; } v; v.u = ((unsigned int)h) << 16;
  return v.f;
}

__global__ __launch_bounds__(512) void lagat_kernel(
    const float* __restrict__ adj,
    const float* __restrict__ feat_node,
    const int* __restrict__ idx,
    const int* __restrict__ head_ids,
    const int* __restrict__ tail_ids,
    const float* __restrict__ transform,
    const float* __restrict__ embed,
    const float* __restrict__ w1, const float* __restrict__ b1,
    const float* __restrict__ w2, const float* __restrict__ b2,
    const float* __restrict__ gamma1, const float* __restrict__ beta1,
    const float* __restrict__ gamma2, const float* __restrict__ beta2,
    float* __restrict__ out)
{
  // hop-loop arrays; Ab/Ib (setup-only) alias Xh/CSTh regions
  __shared__ __align__(16) unsigned short Xh[2][64][XP];   // X hi (bf16)
  __shared__ __align__(16) unsigned short Xl[2][64][XP];   // X lo
  __shared__ __align__(16) unsigned short CSTh[2][64][XP]; // (corr*S)^T bf16
  __shared__ __align__(16) float Sb[2][64][LD];            // running state
  __shared__ __align__(16) float featb[64][LD];            // features
  __shared__ __align__(16) float prm[2][3][64];            // gamma,beta,bias
  __shared__ float reach[2][3][64];
  __shared__ float degs[64];
  __shared__ float corr[2][64];                            // init only

  float (*Ab)[LD] = reinterpret_cast<float(*)[LD]>(&Xh[0][0][0]);   // 17.4KB in 18.4KB
  float (*Ib)[LD] = reinterpret_cast<float(*)[LD]>(&CSTh[0][0][0]);

  const int g = blockIdx.x, tid = threadIdx.x, nb = g * 64;
  const int wv = tid >> 6, lane = tid & 63;
  const int ech = wv >> 2, eslab = (wv & 3) * 16;
  const int ln15 = lane & 15, lg = lane >> 4, lg4 = lg * 4;
  const int iNode = eslab + ln15;

  // ---- P0: global -> LDS ----
  {
    const int r = tid >> 3, c8 = (tid & 7) * 8;
    const float4* asrc = (const float4*)&adj[(size_t)(nb + r) * 4096 + nb + c8];
    *(float4*)&Ab[r][c8]     = asrc[0];
    *(float4*)&Ab[r][c8 + 4] = asrc[1];
    if (c8 < 32) {
      const float4* fs = (const float4*)&feat_node[(size_t)(nb + r) * 32 + c8];
      *(float4*)&Ib[r][c8]     = fs[0];
      *(float4*)&Ib[r][c8 + 4] = fs[1];
    } else {
      const float4* es = (const float4*)&embed[(size_t)idx[nb + r] * 32 + (c8 - 32)];
      *(float4*)&Ib[r][c8]     = es[0];
      *(float4*)&Ib[r][c8 + 4] = es[1];
    }
  }
  if (tid < 384) {
    const int a = tid >> 6, h = tid & 63;
    const float* s6 = (a == 0) ? gamma1 : (a == 1) ? beta1 : (a == 2) ? b1
                    : (a == 3) ? gamma2 : (a == 4) ? beta2 : b2;
    prm[a / 3][a % 3][h] = s6[h];
  }

  // W fragments from global, bf16-hi only (W ~0.01 scale; err budget ok)
  s16x8 wfh[8];
  {
    const float* Wg = ech ? w2 : w1;
#pragma unroll
    for (int ct = 0; ct < 4; ++ct)
#pragma unroll
      for (int ks = 0; ks < 2; ++ks) {
        s16x8 h;
#pragma unroll
        for (int j = 0; j < 8; ++j)
          h[j] = (short)f2bf(Wg[(size_t)(ks * 32 + lg * 8 + j) * 64 + ct * 16 + ln15]);
        wfh[ct * 2 + ks] = h;
      }
  }
  __syncthreads();

  const int hl = head_ids[g] - nb, tl = tail_ids[g] - nb;

  // ---- P1: reach0/1 + degs || transform GEMM (Ib -> featb) ----
  if (tid < 128) {
    const int c = tid >> 6, j = tid & 63;
    const int root = c ? tl : hl;
    reach[c][0][j] = (j == root) ? 1.f : 0.f;
    reach[c][1][j] = (j == root || Ab[root][j] != 0.f) ? 1.f : 0.f;
  } else if (tid < 192) {
    const int i = tid & 63;
    float s = 0.f;
    for (int k = 0; k < 64; ++k) s += Ab[i][k];
    degs[i] = s;
  }
  {
    const int c0g = (tid & 15) * 4, r0g = (tid >> 4) * 2;
    float a0c[4] = {}, a1c[4] = {};
    for (int k = 0; k < 64; ++k) {
      const float4 t4 = *(const float4*)&transform[(size_t)k * 64 + c0g];
      const float a0 = Ib[r0g][k], a1 = Ib[r0g + 1][k];
      a0c[0] = fmaf(a0, t4.x, a0c[0]); a0c[1] = fmaf(a0, t4.y, a0c[1]);
      a0c[2] = fmaf(a0, t4.z, a0c[2]); a0c[3] = fmaf(a0, t4.w, a0c[3]);
      a1c[0] = fmaf(a1, t4.x, a1c[0]); a1c[1] = fmaf(a1, t4.y, a1c[1]);
      a1c[2] = fmaf(a1, t4.z, a1c[2]); a1c[3] = fmaf(a1, t4.w, a1c[3]);
    }
    *(float4*)&featb[r0g][c0g]     = make_float4(a0c[0], a0c[1], a0c[2], a0c[3]);
    *(float4*)&featb[r0g + 1][c0g] = make_float4(a1c[0], a1c[1], a1c[2], a1c[3]);
  }
  __syncthreads();

  // ---- P2: reach2 + corr init (128 thr) ; S init + layer-0 (all) ----
  if (tid < 128) {
    const int c = tid >> 6, j = tid & 63;
    const int root = c ? tl : hl;
    float v = (j == root) ? 1.f : 0.f;
    for (int k = 0; k < 64; ++k)
      if (reach[c][1][k] != 0.f && Ab[k][j] != 0.f) v = 1.f;
    reach[c][2][j] = v;
    const int qr = c ? hl : tl;
    float s = 0.f;
    for (int l4 = 0; l4 < 64; l4 += 4) {
      const float4 q4 = *(const float4*)&featb[qr][l4];
      const float4 f4 = *(const float4*)&featb[j][l4];
      s = fmaf(q4.x, f4.x, s); s = fmaf(q4.y, f4.y, s);
      s = fmaf(q4.z, f4.z, s); s = fmaf(q4.w, f4.w, s);
    }
    corr[c][j] = fabsf(s);
  }
  {
    const int r = tid >> 3, c8 = (tid & 7) * 8;
#pragma unroll
    for (int u = 0; u < 2; ++u) {
      const float4 v = *(const float4*)&featb[r][c8 + 4 * u];
      *(float4*)&Sb[0][r][c8 + 4 * u] = v;
      *(float4*)&Sb[1][r][c8 + 4 * u] = v;
      *(float4*)&out[(size_t)(nb + r) * 256 + c8 + 4 * u] = v;
    }
  }
  // adjacency B-frags (symmetric A: read row iNode) + per-lane preloads
  s16x8 afr[2];
#pragma unroll
  for (int ks = 0; ks < 2; ++ks) {
    s16x8 a;
#pragma unroll
    for (int j = 0; j < 8; ++j)
      a[j] = (short)f2bf(Ab[iNode][ks * 32 + lg * 8 + j]);
    afr[ks] = a;
  }
  const float dnv = 1.f / (degs[iNode] + 1e-8f);
  f32x4 ft4[4];
#pragma unroll
  for (int ct = 0; ct < 4; ++ct)
    ft4[ct] = *(const f32x4*)&featb[iNode][ct * 16 + lg4];
  __syncthreads();

  // ---- P2b: CST init = corr_init[j] * feat[j][c], bf16 ----
  {
    const int ch2 = tid >> 8, t = tid & 255;
    const int c = t >> 2, j0 = (t & 3) * 16;
#pragma unroll
    for (int half = 0; half < 2; ++half) {
      s16x8 hh;
#pragma unroll
      for (int m = 0; m < 8; ++m) {
        const int j = j0 + half * 8 + m;
        hh[m] = (short)f2bf(corr[ch2][j] * featb[j][c]);
      }
      *(s16x8*)&CSTh[ch2][c][j0 + half * 8] = hh;
    }
  }
  __syncthreads();

  const int r8 = tid >> 3, cc8 = (tid & 7) * 8;   // layer-write map
  const int qrowE = ech ? hl : tl;

  for (int hop = 2; hop >= 0; --hop) {
    // deferred layer write (L = 2-hop); reads Sb (synced by prev barrier)
    if (hop != 2) {
      const int L = 2 - hop;
#pragma unroll
      for (int u = 0; u < 2; ++u) {
        const float4 a = *(const float4*)&Sb[0][r8][cc8 + 4 * u];
        const float4 b = *(const float4*)&Sb[1][r8][cc8 + 4 * u];
        *(float4*)&out[(size_t)(nb + r8) * 256 + (size_t)L * 64 + cc8 + 4 * u] =
            make_float4(a.x + b.x, a.y + b.y, a.z + b.z, a.w + b.w);
      }
    }

    // B (MFMA, swapped): up^T[c][i] = sum_j CST[c][j] * A[j][i]; then C+D
    {
      f32x4 acc[4] = {{0,0,0,0},{0,0,0,0},{0,0,0,0},{0,0,0,0}};
#pragma unroll
      for (int ct = 0; ct < 4; ++ct)
#pragma unroll
        for (int ks = 0; ks < 2; ++ks) {
          const s16x8 ah = *(const s16x8*)&CSTh[ech][ct * 16 + ln15][ks * 32 + lg * 8];
          acc[ct] = __builtin_amdgcn_mfma_f32_16x16x32_bf16(ah, afr[ks], acc[ct], 0, 0, 0);
        }
      float x[4][4], smm = 0.f, s2m = 0.f;
#pragma unroll
      for (int ct = 0; ct < 4; ++ct)
#pragma unroll
        for (int r = 0; r < 4; ++r) {
          float z = acc[ct][r];
          z = (z > 0.f) ? z : 0.01f * z;   // leaky_relu slope 0.01
          z *= dnv;
          x[ct][r] = z; smm += z; s2m = fmaf(z, z, s2m);
        }
      smm += __shfl_xor(smm, 16); smm += __shfl_xor(smm, 32);
      s2m += __shfl_xor(s2m, 16); s2m += __shfl_xor(s2m, 32);
      const float mu = smm * 0.015625f;
      const float var = fmaxf(s2m * 0.015625f - mu * mu, 0.f);
      const float rstd = rsqrtf(var + 1e-5f);
      const float fE = reach[ech][hop][iNode];
#pragma unroll
      for (int ct = 0; ct < 4; ++ct) {
        const f32x4 ga4 = *(const f32x4*)&prm[ech][0][ct * 16 + lg4];
        const f32x4 be4 = *(const f32x4*)&prm[ech][1][ct * 16 + lg4];
        ushort4 h4, l4;
        {
          const float xv = fmaf(fE, ft4[ct][0], ga4[0] * (x[ct][0] - mu) * rstd + be4[0]);
          h4.x = f2bf(xv); l4.x = f2bf(xv - bf2f(h4.x));
        }
        {
          const float xv = fmaf(fE, ft4[ct][1], ga4[1] * (x[ct][1] - mu) * rstd + be4[1]);
          h4.y = f2bf(xv); l4.y = f2bf(xv - bf2f(h4.y));
        }
        {
          const float xv = fmaf(fE, ft4[ct][2], ga4[2] * (x[ct][2] - mu) * rstd + be4[2]);
          h4.z = f2bf(xv); l4.z = f2bf(xv - bf2f(h4.z));
        }
        {
          const float xv = fmaf(fE, ft4[ct][3], ga4[3] * (x[ct][3] - mu) * rstd + be4[3]);
          h4.w = f2bf(xv); l4.w = f2bf(xv - bf2f(h4.w));
        }
        *(ushort4*)&Xh[ech][iNode][ct * 16 + lg4] = h4;
        *(ushort4*)&Xl[ech][iNode][ct * 16 + lg4] = l4;
      }
    }
    __syncthreads();

    // E (MFMA, swapped): (X@W)^T[c][i]; S/CST update fused
    {
      s16x8 xh2[2], xl2[2];
#pragma unroll
      for (int ks = 0; ks < 2; ++ks) {
        xh2[ks] = *(const s16x8*)&Xh[ech][iNode][ks * 32 + lg * 8];
        xl2[ks] = *(const s16x8*)&Xl[ech][iNode][ks * 32 + lg * 8];
      }
      f32x4 acc[4];
#pragma unroll
      for (int ct = 0; ct < 4; ++ct) {
        acc[ct] = *(const f32x4*)&prm[ech][2][ct * 16 + lg4];  // bias
#pragma unroll
        for (int ks = 0; ks < 2; ++ks) {
          acc[ct] = __builtin_amdgcn_mfma_f32_16x16x32_bf16(wfh[ct*2+ks], xh2[ks], acc[ct], 0, 0, 0);
          acc[ct] = __builtin_amdgcn_mfma_f32_16x16x32_bf16(wfh[ct*2+ks], xl2[ks], acc[ct], 0, 0, 0);
        }
      }
      float s[4][4], v = 0.f;
#pragma unroll
      for (int ct = 0; ct < 4; ++ct) {
        const f32x4 qe4 = *(const f32x4*)&featb[qrowE][ct * 16 + lg4];
#pragma unroll
        for (int r = 0; r < 4; ++r) {
          const float sv = fmaxf(acc[ct][r], 0.f);
          s[ct][r] = sv;
          v = fmaf(qe4[r], sv, v);
        }
      }
      v += __shfl_xor(v, 16); v += __shfl_xor(v, 32);
      const float vc = fabsf(v);
      const float fE = reach[ech][hop][iNode];
      if (fE != 0.f) {
#pragma unroll
        for (int ct = 0; ct < 4; ++ct) {
          *(float4*)&Sb[ech][iNode][ct * 16 + lg4] =
              make_float4(s[ct][0], s[ct][1], s[ct][2], s[ct][3]);
#pragma unroll
          for (int r = 0; r < 4; ++r)
            CSTh[ech][ct * 16 + lg4 + r][iNode] = f2bf(vc * s[ct][r]);
        }
      }
    }
    __syncthreads();
  }

  // final layer 3 write
  {
#pragma unroll
    for (int u = 0; u < 2; ++u) {
      const float4 a = *(const float4*)&Sb[0][r8][cc8 + 4 * u];
      const float4 b = *(const float4*)&Sb[1][r8][cc8 + 4 * u];
      *(float4*)&out[(size_t)(nb + r8) * 256 + 192 + cc8 + 4 * u] =
          make_float4(a.x + b.x, a.y + b.y, a.z + b.z, a.w + b.w);
    }
  }
}

extern "C" void kernel_launch(void* const* d_in, const int* in_sizes, int n_in,
                              void* d_out, int out_size, void* d_ws, size_t ws_size,
                              hipStream_t stream) {
  const float* adj       = (const float*)d_in[0];
  const float* feat_node = (const float*)d_in[1];
  const int*   idx       = (const int*)d_in[2];
  const int*   head_ids  = (const int*)d_in[3];
  const int*   tail_ids  = (const int*)d_in[4];
  // d_in[5] = graph_indices (implied by block structure, unused)
  const float* transform = (const float*)d_in[6];
  const float* embed     = (const float*)d_in[7];
  const float* w1v    = (const float*)d_in[8];
  const float* b1v    = (const float*)d_in[9];
  const float* w2v    = (const float*)d_in[10];
  const float* b2v    = (const float*)d_in[11];
  const float* gamma1 = (const float*)d_in[12];
  const float* beta1  = (const float*)d_in[13];
  const float* gamma2 = (const float*)d_in[14];
  const float* beta2  = (const float*)d_in[15];

  lagat_kernel<<<64, 512, 0, stream>>>(adj, feat_node, idx, head_ids, tail_ids,
      transform, embed, w1v, b1v, w2v, b2v, gamma1, beta1, gamma2, beta2,
      (float*)d_out);
}

// Round 13
// 24.167 us; speedup vs baseline: 1.6312x; 1.0117x over previous
//
#include <hip/hip_runtime.h>

#define LD 68  // fp32 LDS row stride: 272B
#define XP 72  // bf16 row pitch (ushorts): 144B

typedef float f32x4 __attribute__((ext_vector_type(4)));
typedef short s16x8 __attribute__((ext_vector_type(8)));

__device__ __forceinline__ unsigned short f2bf(float f) {
  union { float f; unsigned int u; } v; v.f = f;
  const unsigned int r = (v.u + 0x7fffu + ((v.u >> 16) & 1u)) >> 16;
  return (unsigned short)r;
}
__device__ __forceinline__ float bf2f(unsigned short h) {
  union { unsigned int u; float f; } v; v.u = ((unsigned int)h) << 16;
  return v.f;
}

__global__ __launch_bounds__(512) void lagat_kernel(
    const float* __restrict__ adj,
    const float* __restrict__ feat_node,
    const int* __restrict__ idx,
    const int* __restrict__ head_ids,
    const int* __restrict__ tail_ids,
    const float* __restrict__ transform,
    const float* __restrict__ embed,
    const float* __restrict__ w1, const float* __restrict__ b1,
    const float* __restrict__ w2, const float* __restrict__ b2,
    const float* __restrict__ gamma1, const float* __restrict__ beta1,
    const float* __restrict__ gamma2, const float* __restrict__ beta2,
    float* __restrict__ out)
{
  // CSTs rows are pi-permuted: storage row rho holds logical channel
  // pi(rho) = bits [b5 b3 b2 b4 b1 b0]; inverse rho(c) = 32a5+16a2+8a4+4a3+a1a0
  __shared__ __align__(16) unsigned short CSTs[2][64][XP]; // (corr*S)^T bf16, pi-rows
  __shared__ __align__(16) float Sb[2][64][LD];            // running state
  __shared__ __align__(16) float featb[64][LD];            // features
  __shared__ __align__(16) float Ab[64][LD];               // adjacency (setup)
  __shared__ __align__(16) float Ib[64][LD];               // init_feat (setup)
  __shared__ __align__(16) float prm[2][3][64];            // gamma,beta,bias
  __shared__ float reach[2][3][64];
  __shared__ float degs[64];
  __shared__ float corr[2][64];                            // init only

  const int g = blockIdx.x, tid = threadIdx.x, nb = g * 64;
  const int wv = tid >> 6, lane = tid & 63;
  const int ech = wv >> 2, eslab = (wv & 3) * 16;
  const int ln15 = lane & 15, lg = lane >> 4, lg4 = lg * 4;
  const int iNode = eslab + ln15;

  // ---- P0: global -> LDS ----
  {
    const int r = tid >> 3, c8 = (tid & 7) * 8;
    const float4* asrc = (const float4*)&adj[(size_t)(nb + r) * 4096 + nb + c8];
    *(float4*)&Ab[r][c8]     = asrc[0];
    *(float4*)&Ab[r][c8 + 4] = asrc[1];
    if (c8 < 32) {
      const float4* fs = (const float4*)&feat_node[(size_t)(nb + r) * 32 + c8];
      *(float4*)&Ib[r][c8]     = fs[0];
      *(float4*)&Ib[r][c8 + 4] = fs[1];
    } else {
      const float4* es = (const float4*)&embed[(size_t)idx[nb + r] * 32 + (c8 - 32)];
      *(float4*)&Ib[r][c8]     = es[0];
      *(float4*)&Ib[r][c8 + 4] = es[1];
    }
  }
  if (tid < 384) {
    const int a = tid >> 6, h = tid & 63;
    const float* s6 = (a == 0) ? gamma1 : (a == 1) ? beta1 : (a == 2) ? b1
                    : (a == 3) ? gamma2 : (a == 4) ? beta2 : b2;
    prm[a / 3][a % 3][h] = s6[h];
  }

  // W fragments from global, bf16-hi only
  s16x8 wfh[8];
  {
    const float* Wg = ech ? w2 : w1;
#pragma unroll
    for (int ct = 0; ct < 4; ++ct)
#pragma unroll
      for (int ks = 0; ks < 2; ++ks) {
        s16x8 h;
#pragma unroll
        for (int j = 0; j < 8; ++j)
          h[j] = (short)f2bf(Wg[(size_t)(ks * 32 + lg * 8 + j) * 64 + ct * 16 + ln15]);
        wfh[ct * 2 + ks] = h;
      }
  }
  __syncthreads();

  const int hl = head_ids[g] - nb, tl = tail_ids[g] - nb;

  // ---- P1: reach0/1 + degs || transform GEMM (Ib -> featb) ----
  if (tid < 128) {
    const int c = tid >> 6, j = tid & 63;
    const int root = c ? tl : hl;
    reach[c][0][j] = (j == root) ? 1.f : 0.f;
    reach[c][1][j] = (j == root || Ab[root][j] != 0.f) ? 1.f : 0.f;
  } else if (tid < 192) {
    const int i = tid & 63;
    float s = 0.f;
    for (int k = 0; k < 64; ++k) s += Ab[i][k];
    degs[i] = s;
  }
  {
    const int c0g = (tid & 15) * 4, r0g = (tid >> 4) * 2;
    float a0c[4] = {}, a1c[4] = {};
    for (int k = 0; k < 64; ++k) {
      const float4 t4 = *(const float4*)&transform[(size_t)k * 64 + c0g];
      const float a0 = Ib[r0g][k], a1 = Ib[r0g + 1][k];
      a0c[0] = fmaf(a0, t4.x, a0c[0]); a0c[1] = fmaf(a0, t4.y, a0c[1]);
      a0c[2] = fmaf(a0, t4.z, a0c[2]); a0c[3] = fmaf(a0, t4.w, a0c[3]);
      a1c[0] = fmaf(a1, t4.x, a1c[0]); a1c[1] = fmaf(a1, t4.y, a1c[1]);
      a1c[2] = fmaf(a1, t4.z, a1c[2]); a1c[3] = fmaf(a1, t4.w, a1c[3]);
    }
    *(float4*)&featb[r0g][c0g]     = make_float4(a0c[0], a0c[1], a0c[2], a0c[3]);
    *(float4*)&featb[r0g + 1][c0g] = make_float4(a1c[0], a1c[1], a1c[2], a1c[3]);
  }
  __syncthreads();

  // ---- P2: reach2 + corr init (128 thr) ; S init + layer-0 (all) ----
  if (tid < 128) {
    const int c = tid >> 6, j = tid & 63;
    const int root = c ? tl : hl;
    float v = (j == root) ? 1.f : 0.f;
    for (int k = 0; k < 64; ++k)
      if (reach[c][1][k] != 0.f && Ab[k][j] != 0.f) v = 1.f;
    reach[c][2][j] = v;
    const int qr = c ? hl : tl;
    float s = 0.f;
    for (int l4 = 0; l4 < 64; l4 += 4) {
      const float4 q4 = *(const float4*)&featb[qr][l4];
      const float4 f4 = *(const float4*)&featb[j][l4];
      s = fmaf(q4.x, f4.x, s); s = fmaf(q4.y, f4.y, s);
      s = fmaf(q4.z, f4.z, s); s = fmaf(q4.w, f4.w, s);
    }
    corr[c][j] = fabsf(s);
  }
  {
    const int r = tid >> 3, c8 = (tid & 7) * 8;
#pragma unroll
    for (int u = 0; u < 2; ++u) {
      const float4 v = *(const float4*)&featb[r][c8 + 4 * u];
      *(float4*)&Sb[0][r][c8 + 4 * u] = v;
      *(float4*)&Sb[1][r][c8 + 4 * u] = v;
      *(float4*)&out[(size_t)(nb + r) * 256 + c8 + 4 * u] = v;
    }
  }
  // adjacency B-frags + per-lane preloads (ft4 uses pi channels)
  s16x8 afr[2];
#pragma unroll
  for (int ks = 0; ks < 2; ++ks) {
    s16x8 a;
#pragma unroll
    for (int j = 0; j < 8; ++j)
      a[j] = (short)f2bf(Ab[iNode][ks * 32 + lg * 8 + j]);
    afr[ks] = a;
  }
  const float dnv = 1.f / (degs[iNode] + 1e-8f);
  f32x4 ft4[4];
#pragma unroll
  for (int ct = 0; ct < 4; ++ct) {
    const int ebase = ((ct >> 1) << 5) + lg * 8 + ((ct & 1) << 2);
    ft4[ct] = *(const f32x4*)&featb[iNode][ebase];
  }
  __syncthreads();

  // ---- P2b: CST init = corr_init[j] * feat[j][c] into pi-permuted rows ----
  {
    const int ch2 = tid >> 8, t = tid & 255;
    const int c = t >> 2, j0 = (t & 3) * 16;
    const int rho = ((c >> 5) & 1) * 32 + ((c >> 2) & 1) * 16 +
                    ((c >> 4) & 1) * 8 + ((c >> 3) & 1) * 4 + (c & 3);
#pragma unroll
    for (int half = 0; half < 2; ++half) {
      s16x8 hh;
#pragma unroll
      for (int m = 0; m < 8; ++m) {
        const int j = j0 + half * 8 + m;
        hh[m] = (short)f2bf(corr[ch2][j] * featb[j][c]);
      }
      *(s16x8*)&CSTs[ch2][rho][j0 + half * 8] = hh;
    }
  }
  __syncthreads();

  const int r8 = tid >> 3, cc8 = (tid & 7) * 8;   // layer-write map
  const int qrowE = ech ? hl : tl;

  for (int hop = 2; hop >= 0; --hop) {
    // deferred layer write (L = 2-hop); reads Sb (synced by prev barrier)
    if (hop != 2) {
      const int L = 2 - hop;
#pragma unroll
      for (int u = 0; u < 2; ++u) {
        const float4 a = *(const float4*)&Sb[0][r8][cc8 + 4 * u];
        const float4 b = *(const float4*)&Sb[1][r8][cc8 + 4 * u];
        *(float4*)&out[(size_t)(nb + r8) * 256 + (size_t)L * 64 + cc8 + 4 * u] =
            make_float4(a.x + b.x, a.y + b.y, a.z + b.z, a.w + b.w);
      }
    }

    // B (MFMA): slot (ct,r) = channel pi(ct*16+lg4+r) of node iNode
    f32x4 accB[4] = {{0,0,0,0},{0,0,0,0},{0,0,0,0},{0,0,0,0}};
#pragma unroll
    for (int ct = 0; ct < 4; ++ct)
#pragma unroll
      for (int ks = 0; ks < 2; ++ks) {
        const s16x8 ah = *(const s16x8*)&CSTs[ech][ct * 16 + ln15][ks * 32 + lg * 8];
        accB[ct] = __builtin_amdgcn_mfma_f32_16x16x32_bf16(ah, afr[ks], accB[ct], 0, 0, 0);
      }
    // epilogue: leaky/deg + LN + gamma/beta + f*feat (pi-channel params)
    float x[4][4];
    {
      float smm = 0.f, s2m = 0.f;
#pragma unroll
      for (int ct = 0; ct < 4; ++ct)
#pragma unroll
        for (int r = 0; r < 4; ++r) {
          float z = accB[ct][r];
          z = (z > 0.f) ? z : 0.01f * z;   // leaky_relu slope 0.01
          z *= dnv;
          x[ct][r] = z; smm += z; s2m = fmaf(z, z, s2m);
        }
      smm += __shfl_xor(smm, 16); smm += __shfl_xor(smm, 32);
      s2m += __shfl_xor(s2m, 16); s2m += __shfl_xor(s2m, 32);
      const float mu = smm * 0.015625f;
      const float var = fmaxf(s2m * 0.015625f - mu * mu, 0.f);
      const float rstd = rsqrtf(var + 1e-5f);
      const float fB = reach[ech][hop][iNode];
#pragma unroll
      for (int ct = 0; ct < 4; ++ct) {
        const int ebase = ((ct >> 1) << 5) + lg * 8 + ((ct & 1) << 2);
        const f32x4 ga4 = *(const f32x4*)&prm[ech][0][ebase];
        const f32x4 be4 = *(const f32x4*)&prm[ech][1][ebase];
#pragma unroll
        for (int r = 0; r < 4; ++r)
          x[ct][r] = fmaf(fB, ft4[ct][r], ga4[r] * (x[ct][r] - mu) * rstd + be4[r]);
      }
    }
    // pack E fragments in-register (slot channel == frag channel by pi)
    s16x8 xh2[2], xl2[2];
#pragma unroll
    for (int ks = 0; ks < 2; ++ks) {
      s16x8 hh, ll;
#pragma unroll
      for (int j = 0; j < 8; ++j) {
        const float xv = x[2 * ks + (j >> 2)][j & 3];
        const unsigned short h = f2bf(xv);
        hh[j] = (short)h;
        ll[j] = (short)f2bf(xv - bf2f(h));
      }
      xh2[ks] = hh; xl2[ks] = ll;
    }
    // E (MFMA): (X@W)^T; relu + corr dot, all in registers
    f32x4 accE[4];
#pragma unroll
    for (int ct = 0; ct < 4; ++ct) {
      accE[ct] = *(const f32x4*)&prm[ech][2][ct * 16 + lg4];  // bias
#pragma unroll
      for (int ks = 0; ks < 2; ++ks) {
        accE[ct] = __builtin_amdgcn_mfma_f32_16x16x32_bf16(wfh[ct*2+ks], xh2[ks], accE[ct], 0, 0, 0);
        accE[ct] = __builtin_amdgcn_mfma_f32_16x16x32_bf16(wfh[ct*2+ks], xl2[ks], accE[ct], 0, 0, 0);
      }
    }
    float s[4][4], v = 0.f;
#pragma unroll
    for (int ct = 0; ct < 4; ++ct) {
      const f32x4 qe4 = *(const f32x4*)&featb[qrowE][ct * 16 + lg4];
#pragma unroll
      for (int r = 0; r < 4; ++r) {
        const float sv = fmaxf(accE[ct][r], 0.f);
        s[ct][r] = sv;
        v = fmaf(qe4[r], sv, v);
      }
    }
    v += __shfl_xor(v, 16); v += __shfl_xor(v, 32);
    const float vc = fabsf(v);
    const float fE = reach[ech][hop][iNode];

    __syncthreads();   // all Sb/CST reads complete before any update

    if (fE != 0.f) {
#pragma unroll
      for (int ct = 0; ct < 4; ++ct) {
        *(float4*)&Sb[ech][iNode][ct * 16 + lg4] =
            make_float4(s[ct][0], s[ct][1], s[ct][2], s[ct][3]);
        if (hop) {
          const int rbase = ((ct >> 1) << 5) + ((lg & 1) << 4) +
                            ((ct & 1) << 3) + ((lg >> 1) << 2);
#pragma unroll
          for (int r = 0; r < 4; ++r)
            CSTs[ech][rbase + r][iNode] = f2bf(vc * s[ct][r]);
        }
      }
    }
    __syncthreads();
  }

  // final layer 3 write
  {
#pragma unroll
    for (int u = 0; u < 2; ++u) {
      const float4 a = *(const float4*)&Sb[0][r8][cc8 + 4 * u];
      const float4 b = *(const float4*)&Sb[1][r8][cc8 + 4 * u];
      *(float4*)&out[(size_t)(nb + r8) * 256 + 192 + cc8 + 4 * u] =
          make_float4(a.x + b.x, a.y + b.y, a.z + b.z, a.w + b.w);
    }
  }
}

extern "C" void kernel_launch(void* const* d_in, const int* in_sizes, int n_in,
                              void* d_out, int out_size, void* d_ws, size_t ws_size,
                              hipStream_t stream) {
  const float* adj       = (const float*)d_in[0];
  const float* feat_node = (const float*)d_in[1];
  const int*   idx       = (const int*)d_in[2];
  const int*   head_ids  = (const int*)d_in[3];
  const int*   tail_ids  = (const int*)d_in[4];
  // d_in[5] = graph_indices (implied by block structure, unused)
  const float* transform = (const float*)d_in[6];
  const float* embed     = (const float*)d_in[7];
  const float* w1v    = (const float*)d_in[8];
  const float* b1v    = (const float*)d_in[9];
  const float* w2v    = (const float*)d_in[10];
  const float* b2v    = (const float*)d_in[11];
  const float* gamma1 = (const float*)d_in[12];
  const float* beta1  = (const float*)d_in[13];
  const float* gamma2 = (const float*)d_in[14];
  const float* beta2  = (const float*)d_in[15];

  lagat_kernel<<<64, 512, 0, stream>>>(adj, feat_node, idx, head_ids, tail_ids,
      transform, embed, w1v, b1v, w2v, b2v, gamma1, beta1, gamma2, beta2,
      (float*)d_out);
}

// Round 14
// 21.277 us; speedup vs baseline: 1.8527x; 1.1358x over previous
//
#include <hip/hip_runtime.h>

#define LD 68  // fp32 LDS row stride: 272B
#define XP 72  // bf16 row pitch (ushorts): 144B

typedef float f32x4 __attribute__((ext_vector_type(4)));
typedef short s16x8 __attribute__((ext_vector_type(8)));
typedef unsigned long long u64;

__device__ __forceinline__ unsigned short f2bf(float f) {
  union { float f; unsigned int u; } v; v.f = f;
  const unsigned int r = (v.u + 0x7fffu + ((v.u >> 16) & 1u)) >> 16;
  return (unsigned short)r;
}
__device__ __forceinline__ float bf2f(unsigned short h) {
  union { unsigned int u; float f; } v; v.u = ((unsigned int)h) << 16;
  return v.f;
}

__global__ __launch_bounds__(512) void lagat_kernel(
    const float* __restrict__ adj,
    const float* __restrict__ feat_node,
    const int* __restrict__ idx,
    const int* __restrict__ head_ids,
    const int* __restrict__ tail_ids,
    const float* __restrict__ transform,
    const float* __restrict__ embed,
    const float* __restrict__ w1, const float* __restrict__ b1,
    const float* __restrict__ w2, const float* __restrict__ b2,
    const float* __restrict__ gamma1, const float* __restrict__ beta1,
    const float* __restrict__ gamma2, const float* __restrict__ beta2,
    float* __restrict__ out)
{
  // CSTs rows are pi-permuted: storage row rho holds logical channel
  // pi(rho) = bits [b5 b3 b2 b4 b1 b0]
  __shared__ __align__(16) unsigned short CSTs[2][64][XP]; // (corr*S)^T bf16
  __shared__ __align__(16) float Sb[2][64][LD];            // running state
  __shared__ __align__(16) float featb[64][LD];            // features
  __shared__ __align__(16) float Ab[64][LD];               // adjacency (setup)
  __shared__ __align__(16) float Ib[64][LD];               // init_feat (setup)
  __shared__ __align__(16) float Wb[2][4096];              // W staged (setup)
  __shared__ __align__(16) float prm[2][3][64];            // gamma,beta,bias
  __shared__ u64 adjbits[64];
  __shared__ u64 lev[2][3];                                // BFS reach masks
  __shared__ float degs[64];
  __shared__ float corr[2][64];                            // init only

  const int g = blockIdx.x, tid = threadIdx.x, nb = g * 64;
  const int wv = tid >> 6, lane = tid & 63;
  const int ech = wv >> 2, eslab = (wv & 3) * 16;
  const int ln15 = lane & 15, lg = lane >> 4, lg4 = lg * 4;
  const int iNode = eslab + ln15;

  // ---- P0: global -> LDS (adj, init_feat, prm, W) ----
  {
    const int r = tid >> 3, c8 = (tid & 7) * 8;
    const float4* asrc = (const float4*)&adj[(size_t)(nb + r) * 4096 + nb + c8];
    *(float4*)&Ab[r][c8]     = asrc[0];
    *(float4*)&Ab[r][c8 + 4] = asrc[1];
    if (c8 < 32) {
      const float4* fs = (const float4*)&feat_node[(size_t)(nb + r) * 32 + c8];
      *(float4*)&Ib[r][c8]     = fs[0];
      *(float4*)&Ib[r][c8 + 4] = fs[1];
    } else {
      const float4* es = (const float4*)&embed[(size_t)idx[nb + r] * 32 + (c8 - 32)];
      *(float4*)&Ib[r][c8]     = es[0];
      *(float4*)&Ib[r][c8 + 4] = es[1];
    }
  }
  {
    const int base = tid * 16;  // 512*16 = 8192 = 2*4096
    const float* src = (base < 4096) ? &w1[base] : &w2[base - 4096];
    float* dst = &Wb[0][0] + base;
#pragma unroll
    for (int u = 0; u < 4; ++u)
      *(float4*)&dst[u * 4] = *(const float4*)&src[u * 4];
  }
  if (tid < 384) {
    const int a = tid >> 6, h = tid & 63;
    const float* s6 = (a == 0) ? gamma1 : (a == 1) ? beta1 : (a == 2) ? b1
                    : (a == 3) ? gamma2 : (a == 4) ? beta2 : b2;
    prm[a / 3][a % 3][h] = s6[h];
  }
  __syncthreads();

  const int hl = head_ids[g] - nb, tl = tail_ids[g] - nb;

  // ---- P1: adjbits+degs (ballot) ; transform GEMM ; W/A frag builds ----
  {
#pragma unroll
    for (int rr = 0; rr < 8; ++rr) {
      const int row = wv * 8 + rr;
      const u64 b = __ballot(Ab[row][lane] != 0.0f);
      if (lane == 0) { adjbits[row] = b; degs[row] = (float)__popcll(b); }
    }
  }
  {
    const int c0g = (tid & 15) * 4, r0g = (tid >> 4) * 2;
    float a0c[4] = {}, a1c[4] = {};
    for (int k = 0; k < 64; ++k) {
      const float4 t4 = *(const float4*)&transform[(size_t)k * 64 + c0g];
      const float a0 = Ib[r0g][k], a1 = Ib[r0g + 1][k];
      a0c[0] = fmaf(a0, t4.x, a0c[0]); a0c[1] = fmaf(a0, t4.y, a0c[1]);
      a0c[2] = fmaf(a0, t4.z, a0c[2]); a0c[3] = fmaf(a0, t4.w, a0c[3]);
      a1c[0] = fmaf(a1, t4.x, a1c[0]); a1c[1] = fmaf(a1, t4.y, a1c[1]);
      a1c[2] = fmaf(a1, t4.z, a1c[2]); a1c[3] = fmaf(a1, t4.w, a1c[3]);
    }
    *(float4*)&featb[r0g][c0g]     = make_float4(a0c[0], a0c[1], a0c[2], a0c[3]);
    *(float4*)&featb[r0g + 1][c0g] = make_float4(a1c[0], a1c[1], a1c[2], a1c[3]);
  }
  // W fragments from Wb LDS (bf16-hi only) + adjacency frags (float4 reads)
  s16x8 wfh[8], afr[2];
  {
    const float* Wl = Wb[ech];
#pragma unroll
    for (int ct = 0; ct < 4; ++ct)
#pragma unroll
      for (int ks = 0; ks < 2; ++ks) {
        s16x8 h;
#pragma unroll
        for (int j = 0; j < 8; ++j)
          h[j] = (short)f2bf(Wl[(ks * 32 + lg * 8 + j) * 64 + ct * 16 + ln15]);
        wfh[ct * 2 + ks] = h;
      }
#pragma unroll
    for (int ks = 0; ks < 2; ++ks) {
      const float4 a0 = *(const float4*)&Ab[iNode][ks * 32 + lg * 8];
      const float4 a1 = *(const float4*)&Ab[iNode][ks * 32 + lg * 8 + 4];
      s16x8 a;
      a[0] = (short)f2bf(a0.x); a[1] = (short)f2bf(a0.y);
      a[2] = (short)f2bf(a0.z); a[3] = (short)f2bf(a0.w);
      a[4] = (short)f2bf(a1.x); a[5] = (short)f2bf(a1.y);
      a[6] = (short)f2bf(a1.z); a[7] = (short)f2bf(a1.w);
      afr[ks] = a;
    }
  }
  __syncthreads();

  // ---- P2: BFS reach (bits, waves 0-1) ; corr init (all) ; S init ----
  if (tid < 128) {
    const int c = wv;                 // chain
    const int root = c ? tl : hl;
    const u64 l0 = 1ull << root;
    const u64 l1 = l0 | adjbits[root];
    u64 cand = ((l1 >> lane) & 1ull) ? adjbits[lane] : 0ull;
#pragma unroll
    for (int m = 1; m < 64; m <<= 1) cand |= __shfl_xor(cand, m, 64);
    if (lane == 0) { lev[c][0] = l0; lev[c][1] = l1; lev[c][2] = l0 | cand; }
  }
  {
    const int ch2 = tid >> 8, t = tid & 255;
    const int j = t >> 2, q = t & 3;
    const int qr = ch2 ? hl : tl;
    float s = 0.f;
#pragma unroll
    for (int u = 0; u < 4; ++u) {
      const float4 q4 = *(const float4*)&featb[qr][q * 16 + 4 * u];
      const float4 f4 = *(const float4*)&featb[j][q * 16 + 4 * u];
      s = fmaf(q4.x, f4.x, s); s = fmaf(q4.y, f4.y, s);
      s = fmaf(q4.z, f4.z, s); s = fmaf(q4.w, f4.w, s);
    }
    s += __shfl_xor(s, 1);
    s += __shfl_xor(s, 2);
    if (q == 0) corr[ch2][j] = fabsf(s);
  }
  {
    const int r = tid >> 3, c8 = (tid & 7) * 8;
#pragma unroll
    for (int u = 0; u < 2; ++u) {
      const float4 v = *(const float4*)&featb[r][c8 + 4 * u];
      *(float4*)&Sb[0][r][c8 + 4 * u] = v;
      *(float4*)&Sb[1][r][c8 + 4 * u] = v;
      *(float4*)&out[(size_t)(nb + r) * 256 + c8 + 4 * u] = v;
    }
  }
  // per-lane hop-invariant preloads
  const float dnv = 1.f / (degs[iNode] + 1e-8f);
  f32x4 ft4[4];
#pragma unroll
  for (int ct = 0; ct < 4; ++ct) {
    const int ebase = ((ct >> 1) << 5) + lg * 8 + ((ct & 1) << 2);
    ft4[ct] = *(const f32x4*)&featb[iNode][ebase];
  }
  __syncthreads();

  // ---- P2b: CST init = corr_init[j] * feat[j][c] into pi-permuted rows ----
  {
    const int ch2 = tid >> 8, t = tid & 255;
    const int c = t >> 2, j0 = (t & 3) * 16;
    const int rho = ((c >> 5) & 1) * 32 + ((c >> 2) & 1) * 16 +
                    ((c >> 4) & 1) * 8 + ((c >> 3) & 1) * 4 + (c & 3);
#pragma unroll
    for (int half = 0; half < 2; ++half) {
      s16x8 hh;
#pragma unroll
      for (int m = 0; m < 8; ++m) {
        const int j = j0 + half * 8 + m;
        hh[m] = (short)f2bf(corr[ch2][j] * featb[j][c]);
      }
      *(s16x8*)&CSTs[ch2][rho][j0 + half * 8] = hh;
    }
  }
  __syncthreads();

  const int r8 = tid >> 3, cc8 = (tid & 7) * 8;   // layer-write map
  const int qrowE = ech ? hl : tl;

  // hoisted hop-invariants: reach bits, query row, bias
  u64 levCh[3];
#pragma unroll
  for (int k = 0; k < 3; ++k) levCh[k] = lev[ech][k];
  f32x4 qe4[4], bias4[4];
#pragma unroll
  for (int ct = 0; ct < 4; ++ct) {
    qe4[ct] = *(const f32x4*)&featb[qrowE][ct * 16 + lg4];
    bias4[ct] = *(const f32x4*)&prm[ech][2][ct * 16 + lg4];
  }

  for (int hop = 2; hop >= 0; --hop) {
    // deferred layer write (L = 2-hop); reads Sb (synced by prev barrier)
    if (hop != 2) {
      const int L = 2 - hop;
#pragma unroll
      for (int u = 0; u < 2; ++u) {
        const float4 a = *(const float4*)&Sb[0][r8][cc8 + 4 * u];
        const float4 b = *(const float4*)&Sb[1][r8][cc8 + 4 * u];
        *(float4*)&out[(size_t)(nb + r8) * 256 + (size_t)L * 64 + cc8 + 4 * u] =
            make_float4(a.x + b.x, a.y + b.y, a.z + b.z, a.w + b.w);
      }
    }

    // B (MFMA): slot (ct,r) = channel pi(ct*16+lg4+r) of node iNode
    f32x4 accB[4] = {{0,0,0,0},{0,0,0,0},{0,0,0,0},{0,0,0,0}};
#pragma unroll
    for (int ct = 0; ct < 4; ++ct)
#pragma unroll
      for (int ks = 0; ks < 2; ++ks) {
        const s16x8 ah = *(const s16x8*)&CSTs[ech][ct * 16 + ln15][ks * 32 + lg * 8];
        accB[ct] = __builtin_amdgcn_mfma_f32_16x16x32_bf16(ah, afr[ks], accB[ct], 0, 0, 0);
      }
    const float fB = (float)((levCh[hop] >> iNode) & 1ull);
    // epilogue: leaky/deg + LN + gamma/beta + f*feat (pi-channel params)
    float x[4][4];
    {
      float smm = 0.f, s2m = 0.f;
#pragma unroll
      for (int ct = 0; ct < 4; ++ct)
#pragma unroll
        for (int r = 0; r < 4; ++r) {
          float z = accB[ct][r];
          z = (z > 0.f) ? z : 0.01f * z;   // leaky_relu slope 0.01
          z *= dnv;
          x[ct][r] = z; smm += z; s2m = fmaf(z, z, s2m);
        }
      smm += __shfl_xor(smm, 16); smm += __shfl_xor(smm, 32);
      s2m += __shfl_xor(s2m, 16); s2m += __shfl_xor(s2m, 32);
      const float mu = smm * 0.015625f;
      const float var = fmaxf(s2m * 0.015625f - mu * mu, 0.f);
      const float rstd = rsqrtf(var + 1e-5f);
#pragma unroll
      for (int ct = 0; ct < 4; ++ct) {
        const int ebase = ((ct >> 1) << 5) + lg * 8 + ((ct & 1) << 2);
        const f32x4 ga4 = *(const f32x4*)&prm[ech][0][ebase];
        const f32x4 be4 = *(const f32x4*)&prm[ech][1][ebase];
#pragma unroll
        for (int r = 0; r < 4; ++r)
          x[ct][r] = fmaf(fB, ft4[ct][r], ga4[r] * (x[ct][r] - mu) * rstd + be4[r]);
      }
    }
    // pack E fragments in-register (slot channel == frag channel by pi)
    s16x8 xh2[2], xl2[2];
#pragma unroll
    for (int ks = 0; ks < 2; ++ks) {
      s16x8 hh, ll;
#pragma unroll
      for (int j = 0; j < 8; ++j) {
        const float xv = x[2 * ks + (j >> 2)][j & 3];
        const unsigned short h = f2bf(xv);
        hh[j] = (short)h;
        ll[j] = (short)f2bf(xv - bf2f(h));
      }
      xh2[ks] = hh; xl2[ks] = ll;
    }
    // E (MFMA): (X@W)^T; relu + corr dot, all in registers
    f32x4 accE[4];
#pragma unroll
    for (int ct = 0; ct < 4; ++ct) {
      accE[ct] = bias4[ct];
#pragma unroll
      for (int ks = 0; ks < 2; ++ks) {
        accE[ct] = __builtin_amdgcn_mfma_f32_16x16x32_bf16(wfh[ct*2+ks], xh2[ks], accE[ct], 0, 0, 0);
        accE[ct] = __builtin_amdgcn_mfma_f32_16x16x32_bf16(wfh[ct*2+ks], xl2[ks], accE[ct], 0, 0, 0);
      }
    }
    float s[4][4], v = 0.f;
#pragma unroll
    for (int ct = 0; ct < 4; ++ct)
#pragma unroll
      for (int r = 0; r < 4; ++r) {
        const float sv = fmaxf(accE[ct][r], 0.f);
        s[ct][r] = sv;
        v = fmaf(qe4[ct][r], sv, v);
      }
    v += __shfl_xor(v, 16); v += __shfl_xor(v, 32);
    const float vc = fabsf(v);
    const float fE = (float)((levCh[hop] >> iNode) & 1ull);

    __syncthreads();   // all Sb/CST reads complete before any update

    if (fE != 0.f) {
#pragma unroll
      for (int ct = 0; ct < 4; ++ct) {
        *(float4*)&Sb[ech][iNode][ct * 16 + lg4] =
            make_float4(s[ct][0], s[ct][1], s[ct][2], s[ct][3]);
        if (hop) {
          const int rbase = ((ct >> 1) << 5) + ((lg & 1) << 4) +
                            ((ct & 1) << 3) + ((lg >> 1) << 2);
#pragma unroll
          for (int r = 0; r < 4; ++r)
            CSTs[ech][rbase + r][iNode] = f2bf(vc * s[ct][r]);
        }
      }
    }
    __syncthreads();
  }

  // final layer 3 write
  {
#pragma unroll
    for (int u = 0; u < 2; ++u) {
      const float4 a = *(const float4*)&Sb[0][r8][cc8 + 4 * u];
      const float4 b = *(const float4*)&Sb[1][r8][cc8 + 4 * u];
      *(float4*)&out[(size_t)(nb + r8) * 256 + 192 + cc8 + 4 * u] =
          make_float4(a.x + b.x, a.y + b.y, a.z + b.z, a.w + b.w);
    }
  }
}

extern "C" void kernel_launch(void* const* d_in, const int* in_sizes, int n_in,
                              void* d_out, int out_size, void* d_ws, size_t ws_size,
                              hipStream_t stream) {
  const float* adj       = (const float*)d_in[0];
  const float* feat_node = (const float*)d_in[1];
  const int*   idx       = (const int*)d_in[2];
  const int*   head_ids  = (const int*)d_in[3];
  const int*   tail_ids  = (const int*)d_in[4];
  // d_in[5] = graph_indices (implied by block structure, unused)
  const float* transform = (const float*)d_in[6];
  const float* embed     = (const float*)d_in[7];
  const float* w1v    = (const float*)d_in[8];
  const float* b1v    = (const float*)d_in[9];
  const float* w2v    = (const float*)d_in[10];
  const float* b2v    = (const float*)d_in[11];
  const float* gamma1 = (const float*)d_in[12];
  const float* beta1  = (const float*)d_in[13];
  const float* gamma2 = (const float*)d_in[14];
  const float* beta2  = (const float*)d_in[15];

  lagat_kernel<<<64, 512, 0, stream>>>(adj, feat_node, idx, head_ids, tail_ids,
      transform, embed, w1v, b1v, w2v, b2v, gamma1, beta1, gamma2, beta2,
      (float*)d_out);
}

// Round 15
// 19.489 us; speedup vs baseline: 2.0227x; 1.0917x over previous
//
#include <hip/hip_runtime.h>

#define LD 68  // fp32 LDS row stride: 272B
#define XP 72  // bf16 row pitch (ushorts): 144B

typedef float f32x4 __attribute__((ext_vector_type(4)));
typedef short s16x8 __attribute__((ext_vector_type(8)));
typedef unsigned long long u64;

__device__ __forceinline__ unsigned short f2bf(float f) {
  union { float f; unsigned int u; } v; v.f = f;
  const unsigned int r = (v.u + 0x7fffu + ((v.u >> 16) & 1u)) >> 16;
  return (unsigned short)r;
}
__device__ __forceinline__ float bf2f(unsigned short h) {
  union { unsigned int u; float f; } v; v.u = ((unsigned int)h) << 16;
  return v.f;
}

__global__ __launch_bounds__(512) void lagat_kernel(
    const float* __restrict__ adj,
    const float* __restrict__ feat_node,
    const int* __restrict__ idx,
    const int* __restrict__ head_ids,
    const int* __restrict__ tail_ids,
    const float* __restrict__ transform,
    const float* __restrict__ embed,
    const float* __restrict__ w1, const float* __restrict__ b1,
    const float* __restrict__ w2, const float* __restrict__ b2,
    const float* __restrict__ gamma1, const float* __restrict__ beta1,
    const float* __restrict__ gamma2, const float* __restrict__ beta2,
    float* __restrict__ out)
{
  // CSTs rows are pi-permuted: storage row rho holds logical channel
  // pi(rho) = bits [b5 b3 b2 b4 b1 b0]
  __shared__ __align__(16) unsigned short CSTs[2][64][XP]; // (corr*S)^T bf16
  __shared__ __align__(16) float Sb[2][64][LD];            // running state
  __shared__ __align__(16) float featb[64][LD];            // features
  __shared__ __align__(16) float Ib[64][LD];               // init_feat (setup)
  __shared__ __align__(16) float Wb[2][4096];              // W staged (setup)
  __shared__ __align__(16) float Tb[4096];                 // transform (setup)
  __shared__ __align__(16) float prm[2][3][64];            // gamma,beta,bias
  __shared__ u64 adjbits[64];
  __shared__ u64 lev[2][3];                                // BFS reach masks
  __shared__ float degs[64];
  __shared__ float corr[2][64];                            // init only

  const int g = blockIdx.x, tid = threadIdx.x, nb = g * 64;
  const int wv = tid >> 6, lane = tid & 63;
  const int ech = wv >> 2, eslab = (wv & 3) * 16;
  const int ln15 = lane & 15, lg = lane >> 4, lg4 = lg * 4;
  const int iNode = eslab + ln15;

  // ---- P0: adj -> bit rows (ballot); init_feat, W, T, prm -> LDS ----
  {
#pragma unroll
    for (int rr = 0; rr < 8; ++rr) {
      const int row = wv * 8 + rr;
      const u64 b = __ballot(adj[(size_t)(nb + row) * 4096 + nb + lane] != 0.0f);
      if (lane == 0) adjbits[row] = b;
    }
  }
  {
    const int r = tid >> 3, c8 = (tid & 7) * 8;
    if (c8 < 32) {
      const float4* fs = (const float4*)&feat_node[(size_t)(nb + r) * 32 + c8];
      *(float4*)&Ib[r][c8]     = fs[0];
      *(float4*)&Ib[r][c8 + 4] = fs[1];
    } else {
      const float4* es = (const float4*)&embed[(size_t)idx[nb + r] * 32 + (c8 - 32)];
      *(float4*)&Ib[r][c8]     = es[0];
      *(float4*)&Ib[r][c8 + 4] = es[1];
    }
  }
  {
    const int base = tid * 16;  // 512*16 = 8192 = 2*4096
    const float* src = (base < 4096) ? &w1[base] : &w2[base - 4096];
    float* dst = &Wb[0][0] + base;
#pragma unroll
    for (int u = 0; u < 4; ++u)
      *(float4*)&dst[u * 4] = *(const float4*)&src[u * 4];
  }
  {
    const int tb = tid * 8;  // 512*8 = 4096
    *(float4*)&Tb[tb]     = *(const float4*)&transform[tb];
    *(float4*)&Tb[tb + 4] = *(const float4*)&transform[tb + 4];
  }
  if (tid < 384) {
    const int a = tid >> 6, h = tid & 63;
    const float* s6 = (a == 0) ? gamma1 : (a == 1) ? beta1 : (a == 2) ? b1
                    : (a == 3) ? gamma2 : (a == 4) ? beta2 : b2;
    prm[a / 3][a % 3][h] = s6[h];
  }
  __syncthreads();

  const int hl = head_ids[g] - nb, tl = tail_ids[g] - nb;

  // ---- P1: degs + BFS (subset) ; W frags (all) ; feat MFMA (ech==0) ----
  if (tid < 64) {
    degs[tid] = (float)__popcll(adjbits[tid]);
  } else if (tid < 192) {
    const int c = (tid >> 6) - 1;     // chain 0 / 1
    const int root = c ? tl : hl;
    const u64 l0 = 1ull << root;
    const u64 l1 = l0 | adjbits[root];
    u64 cand = ((l1 >> lane) & 1ull) ? adjbits[lane] : 0ull;
#pragma unroll
    for (int m = 1; m < 64; m <<= 1) cand |= __shfl_xor(cand, m, 64);
    if (lane == 0) { lev[c][0] = l0; lev[c][1] = l1; lev[c][2] = l0 | cand; }
  }
  // W fragments from Wb LDS (bf16-hi only); adjacency frags from bits
  s16x8 wfh[8], afr[2];
  {
    const float* Wl = Wb[ech];
#pragma unroll
    for (int ct = 0; ct < 4; ++ct)
#pragma unroll
      for (int ks = 0; ks < 2; ++ks) {
        s16x8 h;
#pragma unroll
        for (int j = 0; j < 8; ++j)
          h[j] = (short)f2bf(Wl[(ks * 32 + lg * 8 + j) * 64 + ct * 16 + ln15]);
        wfh[ct * 2 + ks] = h;
      }
    const u64 abits = adjbits[iNode];
#pragma unroll
    for (int ks = 0; ks < 2; ++ks) {
      s16x8 a;
#pragma unroll
      for (int j = 0; j < 8; ++j)
        a[j] = (short)(((abits >> (ks * 32 + lg * 8 + j)) & 1ull) ? 0x3F80 : 0);
      afr[ks] = a;
    }
  }
  // feat = init @ transform via MFMA (waves 0-3 compute+write; dedup)
  if (ech == 0) {
    s16x8 ihf[2], ilf[2];
#pragma unroll
    for (int ks = 0; ks < 2; ++ks) {
      const float4 i0 = *(const float4*)&Ib[iNode][ks * 32 + lg * 8];
      const float4 i1 = *(const float4*)&Ib[iNode][ks * 32 + lg * 8 + 4];
      const float iv[8] = {i0.x, i0.y, i0.z, i0.w, i1.x, i1.y, i1.z, i1.w};
      s16x8 hh, ll;
#pragma unroll
      for (int j = 0; j < 8; ++j) {
        const unsigned short h = f2bf(iv[j]);
        hh[j] = (short)h;
        ll[j] = (short)f2bf(iv[j] - bf2f(h));
      }
      ihf[ks] = hh; ilf[ks] = ll;
    }
    f32x4 facc[4] = {{0,0,0,0},{0,0,0,0},{0,0,0,0},{0,0,0,0}};
#pragma unroll
    for (int ct = 0; ct < 4; ++ct)
#pragma unroll
      for (int ks = 0; ks < 2; ++ks) {
        s16x8 th;
#pragma unroll
        for (int j = 0; j < 8; ++j)
          th[j] = (short)f2bf(Tb[(ks * 32 + lg * 8 + j) * 64 + ct * 16 + ln15]);
        facc[ct] = __builtin_amdgcn_mfma_f32_16x16x32_bf16(th, ihf[ks], facc[ct], 0, 0, 0);
        facc[ct] = __builtin_amdgcn_mfma_f32_16x16x32_bf16(th, ilf[ks], facc[ct], 0, 0, 0);
      }
#pragma unroll
    for (int ct = 0; ct < 4; ++ct)
      *(float4*)&featb[iNode][ct * 16 + lg4] =
          make_float4(facc[ct][0], facc[ct][1], facc[ct][2], facc[ct][3]);
  }
  __syncthreads();

  // ---- P2: corr init (all) ; S init + layer-0 (all) ; preloads ----
  {
    const int ch2 = tid >> 8, t = tid & 255;
    const int j = t >> 2, q = t & 3;
    const int qr = ch2 ? hl : tl;
    float s = 0.f;
#pragma unroll
    for (int u = 0; u < 4; ++u) {
      const float4 q4 = *(const float4*)&featb[qr][q * 16 + 4 * u];
      const float4 f4 = *(const float4*)&featb[j][q * 16 + 4 * u];
      s = fmaf(q4.x, f4.x, s); s = fmaf(q4.y, f4.y, s);
      s = fmaf(q4.z, f4.z, s); s = fmaf(q4.w, f4.w, s);
    }
    s += __shfl_xor(s, 1);
    s += __shfl_xor(s, 2);
    if (q == 0) corr[ch2][j] = fabsf(s);
  }
  {
    const int r = tid >> 3, c8 = (tid & 7) * 8;
#pragma unroll
    for (int u = 0; u < 2; ++u) {
      const float4 v = *(const float4*)&featb[r][c8 + 4 * u];
      *(float4*)&Sb[0][r][c8 + 4 * u] = v;
      *(float4*)&Sb[1][r][c8 + 4 * u] = v;
      *(float4*)&out[(size_t)(nb + r) * 256 + c8 + 4 * u] = v;
    }
  }
  const float dnv = 1.f / (degs[iNode] + 1e-8f);
  f32x4 ft4[4];
#pragma unroll
  for (int ct = 0; ct < 4; ++ct) {
    const int ebase = ((ct >> 1) << 5) + lg * 8 + ((ct & 1) << 2);
    ft4[ct] = *(const f32x4*)&featb[iNode][ebase];
  }
  __syncthreads();

  // ---- P2b: CST init = corr_init[j] * feat[j][c] into pi-permuted rows ----
  {
    const int ch2 = tid >> 8, t = tid & 255;
    const int c = t >> 2, j0 = (t & 3) * 16;
    const int rho = ((c >> 5) & 1) * 32 + ((c >> 2) & 1) * 16 +
                    ((c >> 4) & 1) * 8 + ((c >> 3) & 1) * 4 + (c & 3);
#pragma unroll
    for (int half = 0; half < 2; ++half) {
      s16x8 hh;
#pragma unroll
      for (int m = 0; m < 8; ++m) {
        const int j = j0 + half * 8 + m;
        hh[m] = (short)f2bf(corr[ch2][j] * featb[j][c]);
      }
      *(s16x8*)&CSTs[ch2][rho][j0 + half * 8] = hh;
    }
  }
  __syncthreads();

  const int r8 = tid >> 3, cc8 = (tid & 7) * 8;   // layer-write map
  const int qrowE = ech ? hl : tl;

  // hoisted hop-invariants: reach bits, query row, bias
  u64 levCh[3];
#pragma unroll
  for (int k = 0; k < 3; ++k) levCh[k] = lev[ech][k];
  f32x4 qe4[4], bias4[4];
#pragma unroll
  for (int ct = 0; ct < 4; ++ct) {
    qe4[ct] = *(const f32x4*)&featb[qrowE][ct * 16 + lg4];
    bias4[ct] = *(const f32x4*)&prm[ech][2][ct * 16 + lg4];
  }

  for (int hop = 2; hop >= 0; --hop) {
    // deferred layer write (L = 2-hop); reads Sb (synced by prev barrier)
    if (hop != 2) {
      const int L = 2 - hop;
#pragma unroll
      for (int u = 0; u < 2; ++u) {
        const float4 a = *(const float4*)&Sb[0][r8][cc8 + 4 * u];
        const float4 b = *(const float4*)&Sb[1][r8][cc8 + 4 * u];
        *(float4*)&out[(size_t)(nb + r8) * 256 + (size_t)L * 64 + cc8 + 4 * u] =
            make_float4(a.x + b.x, a.y + b.y, a.z + b.z, a.w + b.w);
      }
    }

    // B (MFMA): slot (ct,r) = channel pi(ct*16+lg4+r) of node iNode
    f32x4 accB[4] = {{0,0,0,0},{0,0,0,0},{0,0,0,0},{0,0,0,0}};
#pragma unroll
    for (int ct = 0; ct < 4; ++ct)
#pragma unroll
      for (int ks = 0; ks < 2; ++ks) {
        const s16x8 ah = *(const s16x8*)&CSTs[ech][ct * 16 + ln15][ks * 32 + lg * 8];
        accB[ct] = __builtin_amdgcn_mfma_f32_16x16x32_bf16(ah, afr[ks], accB[ct], 0, 0, 0);
      }
    const float fB = (float)((levCh[hop] >> iNode) & 1ull);
    // epilogue: leaky/deg + LN + gamma/beta + f*feat (pi-channel params)
    float x[4][4];
    {
      float smm = 0.f, s2m = 0.f;
#pragma unroll
      for (int ct = 0; ct < 4; ++ct)
#pragma unroll
        for (int r = 0; r < 4; ++r) {
          float z = accB[ct][r];
          z = (z > 0.f) ? z : 0.01f * z;   // leaky_relu slope 0.01
          z *= dnv;
          x[ct][r] = z; smm += z; s2m = fmaf(z, z, s2m);
        }
      smm += __shfl_xor(smm, 16); smm += __shfl_xor(smm, 32);
      s2m += __shfl_xor(s2m, 16); s2m += __shfl_xor(s2m, 32);
      const float mu = smm * 0.015625f;
      const float var = fmaxf(s2m * 0.015625f - mu * mu, 0.f);
      const float rstd = rsqrtf(var + 1e-5f);
#pragma unroll
      for (int ct = 0; ct < 4; ++ct) {
        const int ebase = ((ct >> 1) << 5) + lg * 8 + ((ct & 1) << 2);
        const f32x4 ga4 = *(const f32x4*)&prm[ech][0][ebase];
        const f32x4 be4 = *(const f32x4*)&prm[ech][1][ebase];
#pragma unroll
        for (int r = 0; r < 4; ++r)
          x[ct][r] = fmaf(fB, ft4[ct][r], ga4[r] * (x[ct][r] - mu) * rstd + be4[r]);
      }
    }
    // pack E fragments in-register (slot channel == frag channel by pi)
    s16x8 xh2[2], xl2[2];
#pragma unroll
    for (int ks = 0; ks < 2; ++ks) {
      s16x8 hh, ll;
#pragma unroll
      for (int j = 0; j < 8; ++j) {
        const float xv = x[2 * ks + (j >> 2)][j & 3];
        const unsigned short h = f2bf(xv);
        hh[j] = (short)h;
        ll[j] = (short)f2bf(xv - bf2f(h));
      }
      xh2[ks] = hh; xl2[ks] = ll;
    }
    // E (MFMA): (X@W)^T; relu + corr dot, all in registers
    f32x4 accE[4];
#pragma unroll
    for (int ct = 0; ct < 4; ++ct) {
      accE[ct] = bias4[ct];
#pragma unroll
      for (int ks = 0; ks < 2; ++ks) {
        accE[ct] = __builtin_amdgcn_mfma_f32_16x16x32_bf16(wfh[ct*2+ks], xh2[ks], accE[ct], 0, 0, 0);
        accE[ct] = __builtin_amdgcn_mfma_f32_16x16x32_bf16(wfh[ct*2+ks], xl2[ks], accE[ct], 0, 0, 0);
      }
    }
    float s[4][4], v = 0.f;
#pragma unroll
    for (int ct = 0; ct < 4; ++ct)
#pragma unroll
      for (int r = 0; r < 4; ++r) {
        const float sv = fmaxf(accE[ct][r], 0.f);
        s[ct][r] = sv;
        v = fmaf(qe4[ct][r], sv, v);
      }
    v += __shfl_xor(v, 16); v += __shfl_xor(v, 32);
    const float vc = fabsf(v);
    const float fE = (float)((levCh[hop] >> iNode) & 1ull);

    __syncthreads();   // all Sb/CST reads complete before any update

    if (fE != 0.f) {
#pragma unroll
      for (int ct = 0; ct < 4; ++ct) {
        *(float4*)&Sb[ech][iNode][ct * 16 + lg4] =
            make_float4(s[ct][0], s[ct][1], s[ct][2], s[ct][3]);
        if (hop) {
          const int rbase = ((ct >> 1) << 5) + ((lg & 1) << 4) +
                            ((ct & 1) << 3) + ((lg >> 1) << 2);
#pragma unroll
          for (int r = 0; r < 4; ++r)
            CSTs[ech][rbase + r][iNode] = f2bf(vc * s[ct][r]);
        }
      }
    }
    __syncthreads();
  }

  // final layer 3 write
  {
#pragma unroll
    for (int u = 0; u < 2; ++u) {
      const float4 a = *(const float4*)&Sb[0][r8][cc8 + 4 * u];
      const float4 b = *(const float4*)&Sb[1][r8][cc8 + 4 * u];
      *(float4*)&out[(size_t)(nb + r8) * 256 + 192 + cc8 + 4 * u] =
          make_float4(a.x + b.x, a.y + b.y, a.z + b.z, a.w + b.w);
    }
  }
}

extern "C" void kernel_launch(void* const* d_in, const int* in_sizes, int n_in,
                              void* d_out, int out_size, void* d_ws, size_t ws_size,
                              hipStream_t stream) {
  const float* adj       = (const float*)d_in[0];
  const float* feat_node = (const float*)d_in[1];
  const int*   idx       = (const int*)d_in[2];
  const int*   head_ids  = (const int*)d_in[3];
  const int*   tail_ids  = (const int*)d_in[4];
  // d_in[5] = graph_indices (implied by block structure, unused)
  const float* transform = (const float*)d_in[6];
  const float* embed     = (const float*)d_in[7];
  const float* w1v    = (const float*)d_in[8];
  const float* b1v    = (const float*)d_in[9];
  const float* w2v    = (const float*)d_in[10];
  const float* b2v    = (const float*)d_in[11];
  const float* gamma1 = (const float*)d_in[12];
  const float* beta1  = (const float*)d_in[13];
  const float* gamma2 = (const float*)d_in[14];
  const float* beta2  = (const float*)d_in[15];

  lagat_kernel<<<64, 512, 0, stream>>>(adj, feat_node, idx, head_ids, tail_ids,
      transform, embed, w1v, b1v, w2v, b2v, gamma1, beta1, gamma2, beta2,
      (float*)d_out);
}

// Round 16
// 18.354 us; speedup vs baseline: 2.1478x; 1.0618x over previous
//
#include <hip/hip_runtime.h>

#define LD 68  // fp32 LDS row stride: 272B
#define XP 72  // bf16 row pitch (ushorts): 144B

typedef float f32x4 __attribute__((ext_vector_type(4)));
typedef short s16x8 __attribute__((ext_vector_type(8)));
typedef unsigned long long u64;

__device__ __forceinline__ unsigned short f2bf(float f) {
  union { float f; unsigned int u; } v; v.f = f;
  const unsigned int r = (v.u + 0x7fffu + ((v.u >> 16) & 1u)) >> 16;
  return (unsigned short)r;
}
__device__ __forceinline__ float bf2f(unsigned short h) {
  union { unsigned int u; float f; } v; v.u = ((unsigned int)h) << 16;
  return v.f;
}

__global__ __launch_bounds__(512) void lagat_kernel(
    const float* __restrict__ adj,
    const float* __restrict__ feat_node,
    const int* __restrict__ idx,
    const int* __restrict__ head_ids,
    const int* __restrict__ tail_ids,
    const float* __restrict__ transform,
    const float* __restrict__ embed,
    const float* __restrict__ w1, const float* __restrict__ b1,
    const float* __restrict__ w2, const float* __restrict__ b2,
    const float* __restrict__ gamma1, const float* __restrict__ beta1,
    const float* __restrict__ gamma2, const float* __restrict__ beta2,
    float* __restrict__ out)
{
  // CSTs rows are pi-permuted: storage row rho holds logical channel
  // pi(rho) = bits [b5 b3 b2 b4 b1 b0]
  __shared__ __align__(16) unsigned short CSTs[2][64][XP]; // (corr*S)^T bf16
  __shared__ __align__(16) float Sb[2][64][LD];            // running state
  __shared__ __align__(16) float featb[64][LD];            // features
  __shared__ __align__(16) float Ib[64][LD];               // init_feat (setup)
  __shared__ __align__(16) float Wt[2][64][LD];            // W^T staged [c][k]
  __shared__ __align__(16) float Tt[64][LD];               // transform^T [c][k]
  __shared__ __align__(16) float prm[2][3][64];            // gamma,beta,bias
  __shared__ u64 adjbits[64];
  __shared__ u64 lev[2][3];                                // BFS reach masks
  __shared__ float degs[64];

  const int g = blockIdx.x, tid = threadIdx.x, nb = g * 64;
  const int wv = tid >> 6, lane = tid & 63;
  const int ech = wv >> 2, eslab = (wv & 3) * 16;
  const int ln15 = lane & 15, lg = lane >> 4, lg4 = lg * 4;
  const int iNode = eslab + ln15;

  // ---- P0: adj -> bit rows (ballot); init_feat, W^T, T^T, prm -> LDS ----
  {
#pragma unroll
    for (int rr = 0; rr < 8; ++rr) {
      const int row = wv * 8 + rr;
      const u64 b = __ballot(adj[(size_t)(nb + row) * 4096 + nb + lane] != 0.0f);
      if (lane == 0) adjbits[row] = b;
    }
  }
  {
    const int r = tid >> 3, c8 = (tid & 7) * 8;
    if (c8 < 32) {
      const float4* fs = (const float4*)&feat_node[(size_t)(nb + r) * 32 + c8];
      *(float4*)&Ib[r][c8]     = fs[0];
      *(float4*)&Ib[r][c8 + 4] = fs[1];
    } else {
      const float4* es = (const float4*)&embed[(size_t)idx[nb + r] * 32 + (c8 - 32)];
      *(float4*)&Ib[r][c8]     = es[0];
      *(float4*)&Ib[r][c8 + 4] = es[1];
    }
  }
  {
    // W transposed staging: 8192 elems, 16/thread (one 16-wide row chunk)
    const int base = tid * 16;
    const int m = base >> 12, off = base & 4095;
    const int k = off >> 6, c0 = off & 63;
    const float* src = (m ? w2 : w1) + (size_t)k * 64 + c0;
#pragma unroll
    for (int u = 0; u < 4; ++u) {
      const float4 v = *(const float4*)&src[u * 4];
      Wt[m][c0 + 4 * u][k]     = v.x;
      Wt[m][c0 + 4 * u + 1][k] = v.y;
      Wt[m][c0 + 4 * u + 2][k] = v.z;
      Wt[m][c0 + 4 * u + 3][k] = v.w;
    }
  }
  {
    // transform transposed staging: 4096 elems, 8/thread
    const int base = tid * 8;
    const int k = base >> 6, c0 = base & 63;
    const float* src = transform + (size_t)k * 64 + c0;
#pragma unroll
    for (int u = 0; u < 2; ++u) {
      const float4 v = *(const float4*)&src[u * 4];
      Tt[c0 + 4 * u][k]     = v.x;
      Tt[c0 + 4 * u + 1][k] = v.y;
      Tt[c0 + 4 * u + 2][k] = v.z;
      Tt[c0 + 4 * u + 3][k] = v.w;
    }
  }
  if (tid < 384) {
    const int a = tid >> 6, h = tid & 63;
    const float* s6 = (a == 0) ? gamma1 : (a == 1) ? beta1 : (a == 2) ? b1
                    : (a == 3) ? gamma2 : (a == 4) ? beta2 : b2;
    prm[a / 3][a % 3][h] = s6[h];
  }
  __syncthreads();

  const int hl = head_ids[g] - nb, tl = tail_ids[g] - nb;

  // ---- P1: degs + BFS (subset) ; W frags (all) ; feat MFMA (ech==0) ----
  if (tid < 64) {
    degs[tid] = (float)__popcll(adjbits[tid]);
  } else if (tid < 192) {
    const int c = (tid >> 6) - 1;     // chain 0 / 1
    const int root = c ? tl : hl;
    const u64 l0 = 1ull << root;
    const u64 l1 = l0 | adjbits[root];
    u64 cand = ((l1 >> lane) & 1ull) ? adjbits[lane] : 0ull;
#pragma unroll
    for (int m = 1; m < 64; m <<= 1) cand |= __shfl_xor(cand, m, 64);
    if (lane == 0) { lev[c][0] = l0; lev[c][1] = l1; lev[c][2] = l0 | cand; }
  }
  // W fragments from Wt (vector reads); adjacency frags from bits
  s16x8 wfh[8], afr[2];
  {
#pragma unroll
    for (int ct = 0; ct < 4; ++ct)
#pragma unroll
      for (int ks = 0; ks < 2; ++ks) {
        const float4 v0 = *(const float4*)&Wt[ech][ct * 16 + ln15][ks * 32 + lg * 8];
        const float4 v1 = *(const float4*)&Wt[ech][ct * 16 + ln15][ks * 32 + lg * 8 + 4];
        s16x8 h;
        h[0] = (short)f2bf(v0.x); h[1] = (short)f2bf(v0.y);
        h[2] = (short)f2bf(v0.z); h[3] = (short)f2bf(v0.w);
        h[4] = (short)f2bf(v1.x); h[5] = (short)f2bf(v1.y);
        h[6] = (short)f2bf(v1.z); h[7] = (short)f2bf(v1.w);
        wfh[ct * 2 + ks] = h;
      }
    const u64 abits = adjbits[iNode];
#pragma unroll
    for (int ks = 0; ks < 2; ++ks) {
      s16x8 a;
#pragma unroll
      for (int j = 0; j < 8; ++j)
        a[j] = (short)(((abits >> (ks * 32 + lg * 8 + j)) & 1ull) ? 0x3F80 : 0);
      afr[ks] = a;
    }
  }
  // feat = init @ transform via MFMA (waves 0-3 compute+write; dedup)
  if (ech == 0) {
    s16x8 ihf[2], ilf[2];
#pragma unroll
    for (int ks = 0; ks < 2; ++ks) {
      const float4 i0 = *(const float4*)&Ib[iNode][ks * 32 + lg * 8];
      const float4 i1 = *(const float4*)&Ib[iNode][ks * 32 + lg * 8 + 4];
      const float iv[8] = {i0.x, i0.y, i0.z, i0.w, i1.x, i1.y, i1.z, i1.w};
      s16x8 hh, ll;
#pragma unroll
      for (int j = 0; j < 8; ++j) {
        const unsigned short h = f2bf(iv[j]);
        hh[j] = (short)h;
        ll[j] = (short)f2bf(iv[j] - bf2f(h));
      }
      ihf[ks] = hh; ilf[ks] = ll;
    }
    f32x4 facc[4] = {{0,0,0,0},{0,0,0,0},{0,0,0,0},{0,0,0,0}};
#pragma unroll
    for (int ct = 0; ct < 4; ++ct)
#pragma unroll
      for (int ks = 0; ks < 2; ++ks) {
        const float4 t0 = *(const float4*)&Tt[ct * 16 + ln15][ks * 32 + lg * 8];
        const float4 t1 = *(const float4*)&Tt[ct * 16 + ln15][ks * 32 + lg * 8 + 4];
        s16x8 th;
        th[0] = (short)f2bf(t0.x); th[1] = (short)f2bf(t0.y);
        th[2] = (short)f2bf(t0.z); th[3] = (short)f2bf(t0.w);
        th[4] = (short)f2bf(t1.x); th[5] = (short)f2bf(t1.y);
        th[6] = (short)f2bf(t1.z); th[7] = (short)f2bf(t1.w);
        facc[ct] = __builtin_amdgcn_mfma_f32_16x16x32_bf16(th, ihf[ks], facc[ct], 0, 0, 0);
        facc[ct] = __builtin_amdgcn_mfma_f32_16x16x32_bf16(th, ilf[ks], facc[ct], 0, 0, 0);
      }
#pragma unroll
    for (int ct = 0; ct < 4; ++ct)
      *(float4*)&featb[iNode][ct * 16 + lg4] =
          make_float4(facc[ct][0], facc[ct][1], facc[ct][2], facc[ct][3]);
  }
  __syncthreads();

  // ---- P2: S init + layer-0 ; preloads ; corr+CST init via E-path ----
  {
    const int r = tid >> 3, c8 = (tid & 7) * 8;
#pragma unroll
    for (int u = 0; u < 2; ++u) {
      const float4 v = *(const float4*)&featb[r][c8 + 4 * u];
      *(float4*)&Sb[0][r][c8 + 4 * u] = v;
      *(float4*)&Sb[1][r][c8 + 4 * u] = v;
      *(float4*)&out[(size_t)(nb + r) * 256 + c8 + 4 * u] = v;
    }
  }
  const float dnv = 1.f / (degs[iNode] + 1e-8f);
  const int qrowE = ech ? hl : tl;
  u64 levCh[3];
#pragma unroll
  for (int k = 0; k < 3; ++k) levCh[k] = lev[ech][k];
  f32x4 ft4[4], qe4[4], bias4[4];
#pragma unroll
  for (int ct = 0; ct < 4; ++ct) {
    const int ebase = ((ct >> 1) << 5) + lg * 8 + ((ct & 1) << 2);
    ft4[ct] = *(const f32x4*)&featb[iNode][ebase];
    qe4[ct] = *(const f32x4*)&featb[qrowE][ct * 16 + lg4];
    bias4[ct] = *(const f32x4*)&prm[ech][2][ct * 16 + lg4];
  }
  // corr_init[iNode] and CST init, same dataflow as E's update tail
  {
    f32x4 sf4[4];
    float v = 0.f;
#pragma unroll
    for (int ct = 0; ct < 4; ++ct) {
      sf4[ct] = *(const f32x4*)&featb[iNode][ct * 16 + lg4];
#pragma unroll
      for (int r = 0; r < 4; ++r) v = fmaf(qe4[ct][r], sf4[ct][r], v);
    }
    v += __shfl_xor(v, 16); v += __shfl_xor(v, 32);
    const float vc = fabsf(v);
#pragma unroll
    for (int ct = 0; ct < 4; ++ct) {
      const int rbase = ((ct >> 1) << 5) + ((lg & 1) << 4) +
                        ((ct & 1) << 3) + ((lg >> 1) << 2);
#pragma unroll
      for (int r = 0; r < 4; ++r)
        CSTs[ech][rbase + r][iNode] = f2bf(vc * sf4[ct][r]);
    }
  }
  __syncthreads();

  const int r8 = tid >> 3, cc8 = (tid & 7) * 8;   // layer-write map

  for (int hop = 2; hop >= 0; --hop) {
    // deferred layer write (L = 2-hop); reads Sb (synced by prev barrier)
    if (hop != 2) {
      const int L = 2 - hop;
#pragma unroll
      for (int u = 0; u < 2; ++u) {
        const float4 a = *(const float4*)&Sb[0][r8][cc8 + 4 * u];
        const float4 b = *(const float4*)&Sb[1][r8][cc8 + 4 * u];
        *(float4*)&out[(size_t)(nb + r8) * 256 + (size_t)L * 64 + cc8 + 4 * u] =
            make_float4(a.x + b.x, a.y + b.y, a.z + b.z, a.w + b.w);
      }
    }

    // B (MFMA): slot (ct,r) = channel pi(ct*16+lg4+r) of node iNode
    f32x4 accB[4] = {{0,0,0,0},{0,0,0,0},{0,0,0,0},{0,0,0,0}};
#pragma unroll
    for (int ct = 0; ct < 4; ++ct)
#pragma unroll
      for (int ks = 0; ks < 2; ++ks) {
        const s16x8 ah = *(const s16x8*)&CSTs[ech][ct * 16 + ln15][ks * 32 + lg * 8];
        accB[ct] = __builtin_amdgcn_mfma_f32_16x16x32_bf16(ah, afr[ks], accB[ct], 0, 0, 0);
      }
    const float fB = (float)((levCh[hop] >> iNode) & 1ull);
    // epilogue: leaky/deg + LN + gamma/beta + f*feat (pi-channel params)
    float x[4][4];
    {
      float smm = 0.f, s2m = 0.f;
#pragma unroll
      for (int ct = 0; ct < 4; ++ct)
#pragma unroll
        for (int r = 0; r < 4; ++r) {
          float z = accB[ct][r];
          z = (z > 0.f) ? z : 0.01f * z;   // leaky_relu slope 0.01
          z *= dnv;
          x[ct][r] = z; smm += z; s2m = fmaf(z, z, s2m);
        }
      smm += __shfl_xor(smm, 16); smm += __shfl_xor(smm, 32);
      s2m += __shfl_xor(s2m, 16); s2m += __shfl_xor(s2m, 32);
      const float mu = smm * 0.015625f;
      const float var = fmaxf(s2m * 0.015625f - mu * mu, 0.f);
      const float rstd = rsqrtf(var + 1e-5f);
#pragma unroll
      for (int ct = 0; ct < 4; ++ct) {
        const int ebase = ((ct >> 1) << 5) + lg * 8 + ((ct & 1) << 2);
        const f32x4 ga4 = *(const f32x4*)&prm[ech][0][ebase];
        const f32x4 be4 = *(const f32x4*)&prm[ech][1][ebase];
#pragma unroll
        for (int r = 0; r < 4; ++r)
          x[ct][r] = fmaf(fB, ft4[ct][r], ga4[r] * (x[ct][r] - mu) * rstd + be4[r]);
      }
    }
    // pack E fragments in-register (slot channel == frag channel by pi)
    s16x8 xh2[2], xl2[2];
#pragma unroll
    for (int ks = 0; ks < 2; ++ks) {
      s16x8 hh, ll;
#pragma unroll
      for (int j = 0; j < 8; ++j) {
        const float xv = x[2 * ks + (j >> 2)][j & 3];
        const unsigned short h = f2bf(xv);
        hh[j] = (short)h;
        ll[j] = (short)f2bf(xv - bf2f(h));
      }
      xh2[ks] = hh; xl2[ks] = ll;
    }
    // E (MFMA): (X@W)^T; relu + corr dot, all in registers
    f32x4 accE[4];
#pragma unroll
    for (int ct = 0; ct < 4; ++ct) {
      accE[ct] = bias4[ct];
#pragma unroll
      for (int ks = 0; ks < 2; ++ks) {
        accE[ct] = __builtin_amdgcn_mfma_f32_16x16x32_bf16(wfh[ct*2+ks], xh2[ks], accE[ct], 0, 0, 0);
        accE[ct] = __builtin_amdgcn_mfma_f32_16x16x32_bf16(wfh[ct*2+ks], xl2[ks], accE[ct], 0, 0, 0);
      }
    }
    float s[4][4], v = 0.f;
#pragma unroll
    for (int ct = 0; ct < 4; ++ct)
#pragma unroll
      for (int r = 0; r < 4; ++r) {
        const float sv = fmaxf(accE[ct][r], 0.f);
        s[ct][r] = sv;
        v = fmaf(qe4[ct][r], sv, v);
      }
    v += __shfl_xor(v, 16); v += __shfl_xor(v, 32);
    const float vc = fabsf(v);
    const float fE = (float)((levCh[hop] >> iNode) & 1ull);

    __syncthreads();   // all Sb/CST reads complete before any update

    if (fE != 0.f) {
#pragma unroll
      for (int ct = 0; ct < 4; ++ct) {
        *(float4*)&Sb[ech][iNode][ct * 16 + lg4] =
            make_float4(s[ct][0], s[ct][1], s[ct][2], s[ct][3]);
        if (hop) {
          const int rbase = ((ct >> 1) << 5) + ((lg & 1) << 4) +
                            ((ct & 1) << 3) + ((lg >> 1) << 2);
#pragma unroll
          for (int r = 0; r < 4; ++r)
            CSTs[ech][rbase + r][iNode] = f2bf(vc * s[ct][r]);
        }
      }
    }
    __syncthreads();
  }

  // final layer 3 write
  {
#pragma unroll
    for (int u = 0; u < 2; ++u) {
      const float4 a = *(const float4*)&Sb[0][r8][cc8 + 4 * u];
      const float4 b = *(const float4*)&Sb[1][r8][cc8 + 4 * u];
      *(float4*)&out[(size_t)(nb + r8) * 256 + 192 + cc8 + 4 * u] =
          make_float4(a.x + b.x, a.y + b.y, a.z + b.z, a.w + b.w);
    }
  }
}

extern "C" void kernel_launch(void* const* d_in, const int* in_sizes, int n_in,
                              void* d_out, int out_size, void* d_ws, size_t ws_size,
                              hipStream_t stream) {
  const float* adj       = (const float*)d_in[0];
  const float* feat_node = (const float*)d_in[1];
  const int*   idx       = (const int*)d_in[2];
  const int*   head_ids  = (const int*)d_in[3];
  const int*   tail_ids  = (const int*)d_in[4];
  // d_in[5] = graph_indices (implied by block structure, unused)
  const float* transform = (const float*)d_in[6];
  const float* embed     = (const float*)d_in[7];
  const float* w1v    = (const float*)d_in[8];
  const float* b1v    = (const float*)d_in[9];
  const float* w2v    = (const float*)d_in[10];
  const float* b2v    = (const float*)d_in[11];
  const float* gamma1 = (const float*)d_in[12];
  const float* beta1  = (const float*)d_in[13];
  const float* gamma2 = (const float*)d_in[14];
  const float* beta2  = (const float*)d_in[15];

  lagat_kernel<<<64, 512, 0, stream>>>(adj, feat_node, idx, head_ids, tail_ids,
      transform, embed, w1v, b1v, w2v, b2v, gamma1, beta1, gamma2, beta2,
      (float*)d_out);
}